// Round 2
// 484.798 us; speedup vs baseline: 1.0791x; 1.0791x over previous
//
#include <hip/hip_runtime.h>
#include <hip/hip_bf16.h>

#define N_NODES 8192
#define E_EDGES 524288
#define F_IN    256
#define NH      2
#define F_OUT   128
#define C0      256   // NH*F_OUT

typedef float f32x4 __attribute__((ext_vector_type(4)));

// ---------------- GEMM1: h[8192x256] = x[8192x256] @ W[256x256] ----------------
// v2: float4 LDS reads (pad 68 keeps rows 16B-aligned: 68*4=272=17*16)
__global__ __launch_bounds__(256) void gemm_xw_k(const float* __restrict__ A,
                                                 const float* __restrict__ B,
                                                 float* __restrict__ C) {
  const int K = 256, NC = 256;
  __shared__ float As[16][68];  // [k][m]
  __shared__ float Bs[16][68];  // [k][n]
  int bm = blockIdx.y * 64;
  int bn = blockIdx.x * 64;
  int tid = threadIdx.x;
  int tm = (tid >> 4) << 2;
  int tn = (tid & 15) << 2;
  float acc[4][4] = {};
  for (int k0 = 0; k0 < K; k0 += 16) {
#pragma unroll
    for (int i = 0; i < 4; i++) {
      int idx = tid + i * 256;
      int m = idx >> 4, k = idx & 15;
      As[k][m] = A[(bm + m) * K + k0 + k];
    }
#pragma unroll
    for (int i = 0; i < 4; i++) {
      int idx = tid + i * 256;
      int k = idx >> 6, n = idx & 63;
      Bs[k][n] = B[(k0 + k) * NC + bn + n];
    }
    __syncthreads();
#pragma unroll
    for (int k = 0; k < 16; k++) {
      float4 a = *(const float4*)&As[k][tm];
      float4 b = *(const float4*)&Bs[k][tn];
      acc[0][0] += a.x * b.x; acc[0][1] += a.x * b.y; acc[0][2] += a.x * b.z; acc[0][3] += a.x * b.w;
      acc[1][0] += a.y * b.x; acc[1][1] += a.y * b.y; acc[1][2] += a.y * b.z; acc[1][3] += a.y * b.w;
      acc[2][0] += a.z * b.x; acc[2][1] += a.z * b.y; acc[2][2] += a.z * b.z; acc[2][3] += a.z * b.w;
      acc[3][0] += a.w * b.x; acc[3][1] += a.w * b.y; acc[3][2] += a.w * b.z; acc[3][3] += a.w * b.w;
    }
    __syncthreads();
  }
#pragma unroll
  for (int i = 0; i < 4; i++) {
    float4 o = {acc[i][0], acc[i][1], acc[i][2], acc[i][3]};
    *(float4*)&C[(bm + tm + i) * NC + bn + tn] = o;
  }
}

// ---------------- attention scores: a_s[n][h], a_d[n][h] ----------------
// v2: full-row float4 loads, one lane per float4-quad (covers both heads)
__global__ __launch_bounds__(256) void att_scores_k(const float* __restrict__ h,
                                                    const float* __restrict__ att_src,
                                                    const float* __restrict__ att_dst,
                                                    float* __restrict__ a_s,
                                                    float* __restrict__ a_d) {
  int wave = threadIdx.x >> 6;
  int lane = threadIdx.x & 63;
  int node = blockIdx.x * 4 + wave;
  if (node >= N_NODES) return;
  const float4 hv = *(const float4*)(h + (size_t)node * C0 + lane * 4);
  const float4 vs = *(const float4*)(att_src + lane * 4);
  const float4 vd = *(const float4*)(att_dst + lane * 4);
  float s = hv.x * vs.x + hv.y * vs.y + hv.z * vs.z + hv.w * vs.w;
  float d = hv.x * vd.x + hv.y * vd.y + hv.z * vd.z + hv.w * vd.w;
  // reduce within each 32-lane half (lanes 0-31 = head0, 32-63 = head1)
#pragma unroll
  for (int off = 16; off; off >>= 1) {
    s += __shfl_xor(s, off);
    d += __shfl_xor(d, off);
  }
  if (lane == 0)  { a_s[node * 2] = s;     a_d[node * 2] = d; }
  if (lane == 32) { a_s[node * 2 + 1] = s; a_d[node * 2 + 1] = d; }
}

// ---------------- counting sort by dst: histogram ----------------
__global__ __launch_bounds__(256) void hist_k(const int* __restrict__ ei,
                                              int* __restrict__ deg) {
  int e = blockIdx.x * 256 + threadIdx.x;
  if (e < E_EDGES) atomicAdd(&deg[ei[E_EDGES + e]], 1);
}

// ---------------- exclusive scan of 8192 degrees (single block) ----------------
__global__ __launch_bounds__(256) void scan_k(const int* __restrict__ deg,
                                              int* __restrict__ offs,
                                              int* __restrict__ cursor) {
  __shared__ int sums[256];
  int t = threadIdx.x;
  int local[32];
  int s = 0;
#pragma unroll
  for (int i = 0; i < 32; i++) { local[i] = s; s += deg[t * 32 + i]; }
  sums[t] = s;
  __syncthreads();
  for (int off = 1; off < 256; off <<= 1) {
    int u = (t >= off) ? sums[t - off] : 0;
    __syncthreads();
    if (t >= off) sums[t] += u;
    __syncthreads();
  }
  int base = sums[t] - s;   // exclusive prefix for this thread's chunk
#pragma unroll
  for (int i = 0; i < 32; i++) {
    int o = base + local[i];
    offs[t * 32 + i] = o;
    cursor[t * 32 + i] = o;
  }
  if (t == 255) offs[N_NODES] = sums[255];
}

// ---------------- scatter src ids into dst-sorted order ----------------
__global__ __launch_bounds__(256) void scatter_src_k(const int* __restrict__ ei,
                                                     int* __restrict__ cursor,
                                                     int* __restrict__ sorted_src) {
  int e = blockIdx.x * 256 + threadIdx.x;
  if (e < E_EDGES) {
    int d = ei[E_EDGES + e];
    int p = atomicAdd(&cursor[d], 1);
    sorted_src[p] = ei[e];
  }
}

// ---------------- gather: one wave per dst node, fused softmax + message agg ----------------
// v2: 2x unrolled broadcast loop (2 loads in flight), float2 a_s loads
__global__ __launch_bounds__(256) void gat_gather_k(const int* __restrict__ sorted_src,
                                                    const int* __restrict__ offs,
                                                    const float* __restrict__ h,
                                                    const float* __restrict__ a_s,
                                                    const float* __restrict__ a_d,
                                                    float* __restrict__ gat) {
  int wave = threadIdx.x >> 6;
  int lane = threadIdx.x & 63;
  int node = blockIdx.x * 4 + wave;
  if (node >= N_NODES) return;
  int start = offs[node], end = offs[node + 1];
  const float2 adv = *(const float2*)(a_d + node * 2);
  float ad0 = adv.x, ad1 = adv.y;
  int head = lane >> 5;
  float4 acc = {0, 0, 0, 0};
  float den0 = 0, den1 = 0;
  for (int base = start; base < end; base += 64) {
    int idx = base + lane;
    int s = -1;
    float e0 = 0, e1 = 0;
    if (idx < end) {
      s = sorted_src[idx];
      const float2 asv = *(const float2*)(a_s + s * 2);
      float v0 = asv.x + ad0; v0 = v0 > 0.0f ? v0 : 0.2f * v0;
      float v1 = asv.y + ad1; v1 = v1 > 0.0f ? v1 : 0.2f * v1;
      e0 = __expf(v0);
      e1 = __expf(v1);
      den0 += e0; den1 += e1;
    }
    int cnt = min(64, end - base);
    int j = 0;
    for (; j + 2 <= cnt; j += 2) {
      int sj0 = __shfl(s, j);
      int sj1 = __shfl(s, j + 1);
      float a00 = __shfl(e0, j),     a10 = __shfl(e1, j);
      float a01 = __shfl(e0, j + 1), a11 = __shfl(e1, j + 1);
      const float4 hv0 = *(const float4*)(h + (size_t)sj0 * C0 + lane * 4);
      const float4 hv1 = *(const float4*)(h + (size_t)sj1 * C0 + lane * 4);
      float w0 = head ? a10 : a00;
      float w1 = head ? a11 : a01;
      acc.x += hv0.x * w0; acc.y += hv0.y * w0; acc.z += hv0.z * w0; acc.w += hv0.w * w0;
      acc.x += hv1.x * w1; acc.y += hv1.y * w1; acc.z += hv1.z * w1; acc.w += hv1.w * w1;
    }
    if (j < cnt) {
      int sj = __shfl(s, j);
      float x0 = __shfl(e0, j);
      float x1 = __shfl(e1, j);
      float exh = head ? x1 : x0;
      const float4 hv = *(const float4*)(h + (size_t)sj * C0 + lane * 4);
      acc.x += hv.x * exh; acc.y += hv.y * exh;
      acc.z += hv.z * exh; acc.w += hv.w * exh;
    }
  }
  // self-loop (src = dst = node): message on all lanes, denom on lane 0 ONLY
  {
    const float2 asv = *(const float2*)(a_s + node * 2);
    float v0 = asv.x + ad0; v0 = v0 > 0.0f ? v0 : 0.2f * v0;
    float v1 = asv.y + ad1; v1 = v1 > 0.0f ? v1 : 0.2f * v1;
    float e0 = __expf(v0), e1 = __expf(v1);
    if (lane == 0) { den0 += e0; den1 += e1; }
    float exh = head ? e1 : e0;
    const float4 hv = *(const float4*)(h + (size_t)node * C0 + lane * 4);
    acc.x += hv.x * exh; acc.y += hv.y * exh;
    acc.z += hv.z * exh; acc.w += hv.w * exh;
  }
  // wave-reduce denominators
#pragma unroll
  for (int off = 32; off; off >>= 1) {
    den0 += __shfl_xor(den0, off);
    den1 += __shfl_xor(den1, off);
  }
  float denh = head ? den1 : den0;
  float inv = 1.0f / (denh + 1e-16f);
  float4 o = {acc.x * inv, acc.y * inv, acc.z * inv, acc.w * inv};
  *(float4*)(gat + (size_t)node * C0 + lane * 4) = o;
}

// ---------------- fused GEMM + LayerNorm + ReLU per layer ----------------
// v2: k-vectorized float4 LDS reads (pad KDIM+4 keeps 16B alignment)
template <int KDIM, int ODIM, bool APPLY_IN>
__global__ __launch_bounds__(256) void fused_layer_k(const float* __restrict__ in,
                                                     const float* __restrict__ bias_in,
                                                     const float* __restrict__ W,
                                                     const float* __restrict__ b,
                                                     const float* __restrict__ g,
                                                     const float* __restrict__ be,
                                                     float* __restrict__ out) {
  const int TILE = 16;
  const int GROUPS = 256 / ODIM;
  const int NPT = TILE / GROUPS;
  __shared__ float in_t[TILE][KDIM + 4];
  __shared__ float out_t[TILE][ODIM + 1];
  int tid = threadIdx.x;
  int n0 = blockIdx.x * TILE;
  const int KD4 = KDIM / 4;
  for (int idx = tid; idx < TILE * KD4; idx += 256) {
    int n = idx / KD4, k4 = idx % KD4;
    float4 v = *(const float4*)&in[(size_t)(n0 + n) * KDIM + k4 * 4];
    if (APPLY_IN) {
      const float4 bb = *(const float4*)&bias_in[k4 * 4];
      v.x = fmaxf(v.x + bb.x, 0.0f);
      v.y = fmaxf(v.y + bb.y, 0.0f);
      v.z = fmaxf(v.z + bb.z, 0.0f);
      v.w = fmaxf(v.w + bb.w, 0.0f);
    }
    *(float4*)&in_t[n][k4 * 4] = v;
  }
  __syncthreads();
  int jj = tid % ODIM;
  int grp = tid / ODIM;
  float acc[NPT];
#pragma unroll
  for (int t = 0; t < NPT; t++) acc[t] = b[jj];
  for (int k = 0; k < KDIM; k += 4) {
    float w0 = W[(k + 0) * ODIM + jj];
    float w1 = W[(k + 1) * ODIM + jj];
    float w2 = W[(k + 2) * ODIM + jj];
    float w3 = W[(k + 3) * ODIM + jj];
#pragma unroll
    for (int t = 0; t < NPT; t++) {
      float4 v = *(const float4*)&in_t[grp + t * GROUPS][k];
      acc[t] = fmaf(v.w, w3, fmaf(v.z, w2, fmaf(v.y, w1, fmaf(v.x, w0, acc[t]))));
    }
  }
#pragma unroll
  for (int t = 0; t < NPT; t++) out_t[grp + t * GROUPS][jj] = acc[t];
  __syncthreads();
  // LayerNorm across ODIM, 16 threads per node
  const int TPN = 256 / TILE;   // 16
  const int JPT = ODIM / TPN;
  int node = tid / TPN;
  int ln = tid % TPN;
  float v[JPT];
  float s = 0;
#pragma unroll
  for (int q = 0; q < JPT; q++) { v[q] = out_t[node][ln + q * TPN]; s += v[q]; }
#pragma unroll
  for (int m = 1; m < TPN; m <<= 1) s += __shfl_xor(s, m);
  float mu = s / (float)ODIM;
  float vs = 0;
#pragma unroll
  for (int q = 0; q < JPT; q++) { float dd = v[q] - mu; vs += dd * dd; }
#pragma unroll
  for (int m = 1; m < TPN; m <<= 1) vs += __shfl_xor(vs, m);
  float inv = rsqrtf(vs / (float)ODIM + 1e-5f);
#pragma unroll
  for (int q = 0; q < JPT; q++) {
    int j = ln + q * TPN;
    float o = (v[q] - mu) * inv * g[j] + be[j];
    out[(size_t)(n0 + node) * ODIM + j] = fmaxf(o, 0.0f);
  }
}

// ---------------- final projection: z[n] = h2[n] @ w3 + b3 (stored float4) ----------------
__global__ __launch_bounds__(256) void final_z_k(const float* __restrict__ h2,
                                                 const float* __restrict__ w3,
                                                 const float* __restrict__ b3,
                                                 float* __restrict__ z) {
  int n = blockIdx.x * 256 + threadIdx.x;
  if (n >= N_NODES) return;
  float a0 = b3[0], a1 = b3[1], a2 = b3[2];
  const float4* row = (const float4*)(h2 + (size_t)n * 32);
#pragma unroll
  for (int q = 0; q < 8; q++) {
    float4 v = row[q];
    int k = q * 4;
    a0 += v.x * w3[(k + 0) * 3 + 0] + v.y * w3[(k + 1) * 3 + 0] + v.z * w3[(k + 2) * 3 + 0] + v.w * w3[(k + 3) * 3 + 0];
    a1 += v.x * w3[(k + 0) * 3 + 1] + v.y * w3[(k + 1) * 3 + 1] + v.z * w3[(k + 2) * 3 + 1] + v.w * w3[(k + 3) * 3 + 1];
    a2 += v.x * w3[(k + 0) * 3 + 2] + v.y * w3[(k + 1) * 3 + 2] + v.z * w3[(k + 2) * 3 + 2] + v.w * w3[(k + 3) * 3 + 2];
  }
  float4 zz = {a0, a1, a2, 0.0f};
  ((float4*)z)[n] = zz;
}

// ---------------- cdist: out[i][j] = ||z_i - z_j|| ----------------
// v2: nontemporal stores via native clang vector (256 MiB streaming output, never re-read)
__global__ __launch_bounds__(256) void cdist_k(const float* __restrict__ z,
                                               float* __restrict__ out) {
  int i = blockIdx.x >> 3;
  int j0 = (((blockIdx.x & 7) << 8) + threadIdx.x) << 2;  // first of 4 nodes
  const float4 zi = ((const float4*)z)[i];
  f32x4 r;
  {
    float4 zj = ((const float4*)z)[j0 + 0];
    float dx = zi.x - zj.x, dy = zi.y - zj.y, dz = zi.z - zj.z;
    r.x = sqrtf(dx * dx + dy * dy + dz * dz);
  }
  {
    float4 zj = ((const float4*)z)[j0 + 1];
    float dx = zi.x - zj.x, dy = zi.y - zj.y, dz = zi.z - zj.z;
    r.y = sqrtf(dx * dx + dy * dy + dz * dz);
  }
  {
    float4 zj = ((const float4*)z)[j0 + 2];
    float dx = zi.x - zj.x, dy = zi.y - zj.y, dz = zi.z - zj.z;
    r.z = sqrtf(dx * dx + dy * dy + dz * dz);
  }
  {
    float4 zj = ((const float4*)z)[j0 + 3];
    float dx = zi.x - zj.x, dy = zi.y - zj.y, dz = zi.z - zj.z;
    r.w = sqrtf(dx * dx + dy * dy + dz * dz);
  }
  f32x4* dst = (f32x4*)out + (((size_t)i * N_NODES + j0) >> 2);
  __builtin_nontemporal_store(r, dst);
}

extern "C" void kernel_launch(void* const* d_in, const int* in_sizes, int n_in,
                              void* d_out, int out_size, void* d_ws, size_t ws_size,
                              hipStream_t stream) {
  const float* x        = (const float*)d_in[0];
  const int*   ei       = (const int*)d_in[1];
  const float* W_gat    = (const float*)d_in[2];
  const float* att_src  = (const float*)d_in[3];
  const float* att_dst  = (const float*)d_in[4];
  const float* bias_gat = (const float*)d_in[5];
  const float* w_a      = (const float*)d_in[6];
  const float* b_a      = (const float*)d_in[7];
  const float* g_a      = (const float*)d_in[8];
  const float* be_a     = (const float*)d_in[9];
  const float* w1       = (const float*)d_in[10];
  const float* b1       = (const float*)d_in[11];
  const float* g1       = (const float*)d_in[12];
  const float* be1      = (const float*)d_in[13];
  const float* w2       = (const float*)d_in[14];
  const float* b2       = (const float*)d_in[15];
  const float* g2       = (const float*)d_in[16];
  const float* be2      = (const float*)d_in[17];
  const float* w3       = (const float*)d_in[18];
  const float* b3       = (const float*)d_in[19];
  float* out = (float*)d_out;

  float* ws = (float*)d_ws;
  float* h     = ws;                      // 8192*256
  float* a_s   = h + 2097152;             // 8192*2
  float* a_d   = a_s + 16384;             // 8192*2
  float* gat   = a_d + 16384;             // 8192*256
  float* hA    = gat + 2097152;           // 8192*128
  float* h1    = hA + 1048576;            // 8192*64
  float* h2    = h1 + 524288;             // 8192*32
  float* z     = h2 + 262144;             // 8192*4
  int*   deg    = (int*)(z + 32768);      // 8192
  int*   offs   = deg + 8192;             // 8193 (+pad)
  int*   cursor = offs + 8200;            // 8192
  int*   sorted = cursor + 8192;          // 524288

  // zero the histogram
  hipMemsetAsync(deg, 0, N_NODES * sizeof(int), stream);

  // 1. h = x @ W_gat
  gemm_xw_k<<<dim3(4, 128), 256, 0, stream>>>(x, W_gat, h);
  // 2. attention scores
  att_scores_k<<<2048, 256, 0, stream>>>(h, att_src, att_dst, a_s, a_d);
  // 3. counting sort by dst
  hist_k<<<E_EDGES / 256, 256, 0, stream>>>(ei, deg);
  scan_k<<<1, 256, 0, stream>>>(deg, offs, cursor);
  scatter_src_k<<<E_EDGES / 256, 256, 0, stream>>>(ei, cursor, sorted);
  // 4. fused softmax + message aggregation (gather, no atomics)
  gat_gather_k<<<2048, 256, 0, stream>>>(sorted, offs, h, a_s, a_d, gat);
  // 5. fused layers
  fused_layer_k<256, 128, true><<<N_NODES / 16, 256, 0, stream>>>(gat, bias_gat, w_a, b_a, g_a, be_a, hA);
  fused_layer_k<128, 64, false><<<N_NODES / 16, 256, 0, stream>>>(hA, nullptr, w1, b1, g1, be1, h1);
  fused_layer_k<64, 32, false><<<N_NODES / 16, 256, 0, stream>>>(h1, nullptr, w2, b2, g2, be2, h2);
  // 6. final projection to 3D
  final_z_k<<<N_NODES / 256, 256, 0, stream>>>(h2, w3, b3, z);
  // 7. pairwise distances
  cdist_k<<<N_NODES * 8, 256, 0, stream>>>(z, out);
}

// Round 3
// 481.922 us; speedup vs baseline: 1.0855x; 1.0060x over previous
//
#include <hip/hip_runtime.h>
#include <hip/hip_bf16.h>

#define N_NODES 8192
#define E_EDGES 524288
#define F_IN    256
#define NH      2
#define F_OUT   128
#define C0      256   // NH*F_OUT
#define E_TOT   (E_EDGES + N_NODES)   // edges + self-loops

typedef float f32x4 __attribute__((ext_vector_type(4)));

// ---------------- GEMM1: h[8192x256] = x[8192x256] @ W[256x256] ----------------
__global__ __launch_bounds__(256) void gemm_xw_k(const float* __restrict__ A,
                                                 const float* __restrict__ B,
                                                 float* __restrict__ C) {
  const int K = 256, NC = 256;
  __shared__ float As[16][68];  // [k][m]  (pad 68: rows stay 16B-aligned)
  __shared__ float Bs[16][68];  // [k][n]
  int bm = blockIdx.y * 64;
  int bn = blockIdx.x * 64;
  int tid = threadIdx.x;
  int tm = (tid >> 4) << 2;
  int tn = (tid & 15) << 2;
  float acc[4][4] = {};
  for (int k0 = 0; k0 < K; k0 += 16) {
#pragma unroll
    for (int i = 0; i < 4; i++) {
      int idx = tid + i * 256;
      int m = idx >> 4, k = idx & 15;
      As[k][m] = A[(bm + m) * K + k0 + k];
    }
#pragma unroll
    for (int i = 0; i < 4; i++) {
      int idx = tid + i * 256;
      int k = idx >> 6, n = idx & 63;
      Bs[k][n] = B[(k0 + k) * NC + bn + n];
    }
    __syncthreads();
#pragma unroll
    for (int k = 0; k < 16; k++) {
      float4 a = *(const float4*)&As[k][tm];
      float4 b = *(const float4*)&Bs[k][tn];
      acc[0][0] += a.x * b.x; acc[0][1] += a.x * b.y; acc[0][2] += a.x * b.z; acc[0][3] += a.x * b.w;
      acc[1][0] += a.y * b.x; acc[1][1] += a.y * b.y; acc[1][2] += a.y * b.z; acc[1][3] += a.y * b.w;
      acc[2][0] += a.z * b.x; acc[2][1] += a.z * b.y; acc[2][2] += a.z * b.z; acc[2][3] += a.z * b.w;
      acc[3][0] += a.w * b.x; acc[3][1] += a.w * b.y; acc[3][2] += a.w * b.z; acc[3][3] += a.w * b.w;
    }
    __syncthreads();
  }
#pragma unroll
  for (int i = 0; i < 4; i++) {
    float4 o = {acc[i][0], acc[i][1], acc[i][2], acc[i][3]};
    *(float4*)&C[(bm + tm + i) * NC + bn + tn] = o;
  }
}

// ---------------- attention scores: a_s[n][h], a_d[n][h] ----------------
__global__ __launch_bounds__(256) void att_scores_k(const float* __restrict__ h,
                                                    const float* __restrict__ att_src,
                                                    const float* __restrict__ att_dst,
                                                    float* __restrict__ a_s,
                                                    float* __restrict__ a_d) {
  int wave = threadIdx.x >> 6;
  int lane = threadIdx.x & 63;
  int node = blockIdx.x * 4 + wave;
  if (node >= N_NODES) return;
  const float4 hv = *(const float4*)(h + (size_t)node * C0 + lane * 4);
  const float4 vs = *(const float4*)(att_src + lane * 4);
  const float4 vd = *(const float4*)(att_dst + lane * 4);
  float s = hv.x * vs.x + hv.y * vs.y + hv.z * vs.z + hv.w * vs.w;
  float d = hv.x * vd.x + hv.y * vd.y + hv.z * vd.z + hv.w * vd.w;
#pragma unroll
  for (int off = 16; off; off >>= 1) {
    s += __shfl_xor(s, off);
    d += __shfl_xor(d, off);
  }
  if (lane == 0)  { a_s[node * 2] = s;     a_d[node * 2] = d; }
  if (lane == 32) { a_s[node * 2 + 1] = s; a_d[node * 2 + 1] = d; }
}

// ---------------- counting sort by dst: histogram (real edges only) ----------------
__global__ __launch_bounds__(256) void hist_k(const int* __restrict__ ei,
                                              int* __restrict__ deg) {
  int e = blockIdx.x * 256 + threadIdx.x;
  if (e < E_EDGES) atomicAdd(&deg[ei[E_EDGES + e]], 1);
}

// ---------------- exclusive scan of (deg+1) per node (single block) ----------------
// +1 accounts for the self-loop, which becomes a regular sorted entry.
__global__ __launch_bounds__(256) void scan_k(const int* __restrict__ deg,
                                              int* __restrict__ offs,
                                              int* __restrict__ cursor) {
  __shared__ int sums[256];
  int t = threadIdx.x;
  int local[32];
  int s = 0;
#pragma unroll
  for (int i = 0; i < 32; i++) { local[i] = s; s += deg[t * 32 + i] + 1; }
  sums[t] = s;
  __syncthreads();
  for (int off = 1; off < 256; off <<= 1) {
    int u = (t >= off) ? sums[t - off] : 0;
    __syncthreads();
    if (t >= off) sums[t] += u;
    __syncthreads();
  }
  int base = sums[t] - s;   // exclusive prefix for this thread's chunk
#pragma unroll
  for (int i = 0; i < 32; i++) {
    int o = base + local[i];
    offs[t * 32 + i] = o;
    cursor[t * 32 + i] = o;
  }
  if (t == 255) offs[N_NODES] = sums[255];   // == E_TOT
}

// ---------------- scatter: sorted src ids + precomputed per-edge exp (both heads) ----------------
// Items >= E_EDGES are the self-loops (src = dst = e - E_EDGES).
__global__ __launch_bounds__(256) void scatter_k(const int* __restrict__ ei,
                                                 const float* __restrict__ a_s,
                                                 const float* __restrict__ a_d,
                                                 int* __restrict__ cursor,
                                                 int* __restrict__ sorted_src,
                                                 float2* __restrict__ exv) {
  int e = blockIdx.x * 256 + threadIdx.x;
  if (e >= E_TOT) return;
  int s, d;
  if (e < E_EDGES) { s = ei[e]; d = ei[E_EDGES + e]; }
  else             { s = d = e - E_EDGES; }
  const float2 as = ((const float2*)a_s)[s];
  const float2 ad = ((const float2*)a_d)[d];
  float v0 = as.x + ad.x; v0 = v0 > 0.0f ? v0 : 0.2f * v0;
  float v1 = as.y + ad.y; v1 = v1 > 0.0f ? v1 : 0.2f * v1;
  int p = atomicAdd(&cursor[d], 1);
  sorted_src[p] = s;
  exv[p] = make_float2(__expf(v0), __expf(v1));
}

// ---------------- gather: one wave per dst node, no shfl, no exp ----------------
// Loop counter promoted to SGPR via readfirstlane -> sorted_src/exv loads scalarize.
// Every lane accumulates the full denominator for its head (no reduction needed).
__global__ __launch_bounds__(256) void gat_gather_k(const int* __restrict__ sorted_src,
                                                    const float2* __restrict__ exv,
                                                    const int* __restrict__ offs,
                                                    const float* __restrict__ h,
                                                    float* __restrict__ gat) {
  int wave = threadIdx.x >> 6;
  int lane = threadIdx.x & 63;
  int node = blockIdx.x * 4 + wave;
  if (node >= N_NODES) return;
  int start = __builtin_amdgcn_readfirstlane(offs[node]);
  int end   = __builtin_amdgcn_readfirstlane(offs[node + 1]);
  int head = lane >> 5;
  float4 acc = {0, 0, 0, 0};
  float den = 0.0f;
  int e = start;
  for (; e + 2 <= end; e += 2) {
    int s0 = sorted_src[e];
    int s1 = sorted_src[e + 1];
    float2 x0 = exv[e];
    float2 x1 = exv[e + 1];
    const float4 hv0 = *(const float4*)(h + (size_t)s0 * C0 + lane * 4);
    const float4 hv1 = *(const float4*)(h + (size_t)s1 * C0 + lane * 4);
    float w0 = head ? x0.y : x0.x;
    float w1 = head ? x1.y : x1.x;
    den += w0; den += w1;
    acc.x = fmaf(hv0.x, w0, acc.x); acc.y = fmaf(hv0.y, w0, acc.y);
    acc.z = fmaf(hv0.z, w0, acc.z); acc.w = fmaf(hv0.w, w0, acc.w);
    acc.x = fmaf(hv1.x, w1, acc.x); acc.y = fmaf(hv1.y, w1, acc.y);
    acc.z = fmaf(hv1.z, w1, acc.z); acc.w = fmaf(hv1.w, w1, acc.w);
  }
  if (e < end) {
    int s0 = sorted_src[e];
    float2 x0 = exv[e];
    const float4 hv0 = *(const float4*)(h + (size_t)s0 * C0 + lane * 4);
    float w0 = head ? x0.y : x0.x;
    den += w0;
    acc.x = fmaf(hv0.x, w0, acc.x); acc.y = fmaf(hv0.y, w0, acc.y);
    acc.z = fmaf(hv0.z, w0, acc.z); acc.w = fmaf(hv0.w, w0, acc.w);
  }
  float inv = 1.0f / (den + 1e-16f);
  float4 o = {acc.x * inv, acc.y * inv, acc.z * inv, acc.w * inv};
  *(float4*)(gat + (size_t)node * C0 + lane * 4) = o;
}

// ---------------- fused GEMM + LayerNorm + ReLU per layer (+ optional z projection) ----------------
template <int KDIM, int ODIM, bool APPLY_IN, bool FUSE_Z>
__global__ __launch_bounds__(256) void fused_layer_k(const float* __restrict__ in,
                                                     const float* __restrict__ bias_in,
                                                     const float* __restrict__ W,
                                                     const float* __restrict__ b,
                                                     const float* __restrict__ g,
                                                     const float* __restrict__ be,
                                                     float* __restrict__ out,
                                                     const float* __restrict__ w3,
                                                     const float* __restrict__ b3,
                                                     float* __restrict__ zout) {
  const int TILE = 16;
  const int GROUPS = 256 / ODIM;
  const int NPT = TILE / GROUPS;
  __shared__ float in_t[TILE][KDIM + 4];
  __shared__ float out_t[TILE][ODIM + 1];
  int tid = threadIdx.x;
  int n0 = blockIdx.x * TILE;
  const int KD4 = KDIM / 4;
  for (int idx = tid; idx < TILE * KD4; idx += 256) {
    int n = idx / KD4, k4 = idx % KD4;
    float4 v = *(const float4*)&in[(size_t)(n0 + n) * KDIM + k4 * 4];
    if (APPLY_IN) {
      const float4 bb = *(const float4*)&bias_in[k4 * 4];
      v.x = fmaxf(v.x + bb.x, 0.0f);
      v.y = fmaxf(v.y + bb.y, 0.0f);
      v.z = fmaxf(v.z + bb.z, 0.0f);
      v.w = fmaxf(v.w + bb.w, 0.0f);
    }
    *(float4*)&in_t[n][k4 * 4] = v;
  }
  __syncthreads();
  int jj = tid % ODIM;
  int grp = tid / ODIM;
  float acc[NPT];
#pragma unroll
  for (int t = 0; t < NPT; t++) acc[t] = b[jj];
  for (int k = 0; k < KDIM; k += 4) {
    float w0 = W[(k + 0) * ODIM + jj];
    float w1 = W[(k + 1) * ODIM + jj];
    float w2 = W[(k + 2) * ODIM + jj];
    float w3v = W[(k + 3) * ODIM + jj];
#pragma unroll
    for (int t = 0; t < NPT; t++) {
      float4 v = *(const float4*)&in_t[grp + t * GROUPS][k];
      acc[t] = fmaf(v.w, w3v, fmaf(v.z, w2, fmaf(v.y, w1, fmaf(v.x, w0, acc[t]))));
    }
  }
#pragma unroll
  for (int t = 0; t < NPT; t++) out_t[grp + t * GROUPS][jj] = acc[t];
  __syncthreads();
  // LayerNorm across ODIM, 16 threads per node
  const int TPN = 256 / TILE;   // 16
  const int JPT = ODIM / TPN;
  int node = tid / TPN;
  int ln = tid % TPN;
  float v[JPT];
  float s = 0;
#pragma unroll
  for (int q = 0; q < JPT; q++) { v[q] = out_t[node][ln + q * TPN]; s += v[q]; }
#pragma unroll
  for (int m = 1; m < TPN; m <<= 1) s += __shfl_xor(s, m);
  float mu = s / (float)ODIM;
  float vs = 0;
#pragma unroll
  for (int q = 0; q < JPT; q++) { float dd = v[q] - mu; vs += dd * dd; }
#pragma unroll
  for (int m = 1; m < TPN; m <<= 1) vs += __shfl_xor(vs, m);
  float inv = rsqrtf(vs / (float)ODIM + 1e-5f);
  if (FUSE_Z) {
    // z[node] = relu(ln(h2)) @ w3 + b3, reduced across the 16 lanes of the node
    float p0 = 0, p1 = 0, p2 = 0;
#pragma unroll
    for (int q = 0; q < JPT; q++) {
      int j = ln + q * TPN;
      float val = fmaxf((v[q] - mu) * inv * g[j] + be[j], 0.0f);
      p0 = fmaf(val, w3[j * 3 + 0], p0);
      p1 = fmaf(val, w3[j * 3 + 1], p1);
      p2 = fmaf(val, w3[j * 3 + 2], p2);
    }
#pragma unroll
    for (int m = 1; m < TPN; m <<= 1) {
      p0 += __shfl_xor(p0, m);
      p1 += __shfl_xor(p1, m);
      p2 += __shfl_xor(p2, m);
    }
    if (ln == 0) {
      float4 zz = {p0 + b3[0], p1 + b3[1], p2 + b3[2], 0.0f};
      ((float4*)zout)[n0 + node] = zz;
    }
  } else {
#pragma unroll
    for (int q = 0; q < JPT; q++) {
      int j = ln + q * TPN;
      float o = (v[q] - mu) * inv * g[j] + be[j];
      out[(size_t)(n0 + node) * ODIM + j] = fmaxf(o, 0.0f);
    }
  }
}

// ---------------- cdist: out[i][j] = ||z_i - z_j|| (nontemporal stores) ----------------
__global__ __launch_bounds__(256) void cdist_k(const float* __restrict__ z,
                                               float* __restrict__ out) {
  int i = blockIdx.x >> 3;
  int j0 = (((blockIdx.x & 7) << 8) + threadIdx.x) << 2;  // first of 4 nodes
  const float4 zi = ((const float4*)z)[i];
  f32x4 r;
  {
    float4 zj = ((const float4*)z)[j0 + 0];
    float dx = zi.x - zj.x, dy = zi.y - zj.y, dz = zi.z - zj.z;
    r.x = sqrtf(dx * dx + dy * dy + dz * dz);
  }
  {
    float4 zj = ((const float4*)z)[j0 + 1];
    float dx = zi.x - zj.x, dy = zi.y - zj.y, dz = zi.z - zj.z;
    r.y = sqrtf(dx * dx + dy * dy + dz * dz);
  }
  {
    float4 zj = ((const float4*)z)[j0 + 2];
    float dx = zi.x - zj.x, dy = zi.y - zj.y, dz = zi.z - zj.z;
    r.z = sqrtf(dx * dx + dy * dy + dz * dz);
  }
  {
    float4 zj = ((const float4*)z)[j0 + 3];
    float dx = zi.x - zj.x, dy = zi.y - zj.y, dz = zi.z - zj.z;
    r.w = sqrtf(dx * dx + dy * dy + dz * dz);
  }
  f32x4* dst = (f32x4*)out + (((size_t)i * N_NODES + j0) >> 2);
  __builtin_nontemporal_store(r, dst);
}

extern "C" void kernel_launch(void* const* d_in, const int* in_sizes, int n_in,
                              void* d_out, int out_size, void* d_ws, size_t ws_size,
                              hipStream_t stream) {
  const float* x        = (const float*)d_in[0];
  const int*   ei       = (const int*)d_in[1];
  const float* W_gat    = (const float*)d_in[2];
  const float* att_src  = (const float*)d_in[3];
  const float* att_dst  = (const float*)d_in[4];
  const float* bias_gat = (const float*)d_in[5];
  const float* w_a      = (const float*)d_in[6];
  const float* b_a      = (const float*)d_in[7];
  const float* g_a      = (const float*)d_in[8];
  const float* be_a     = (const float*)d_in[9];
  const float* w1       = (const float*)d_in[10];
  const float* b1       = (const float*)d_in[11];
  const float* g1       = (const float*)d_in[12];
  const float* be1      = (const float*)d_in[13];
  const float* w2       = (const float*)d_in[14];
  const float* b2       = (const float*)d_in[15];
  const float* g2       = (const float*)d_in[16];
  const float* be2      = (const float*)d_in[17];
  const float* w3       = (const float*)d_in[18];
  const float* b3       = (const float*)d_in[19];
  float* out = (float*)d_out;

  float* ws = (float*)d_ws;
  float*  h      = ws;                          // 8192*256      = 2097152
  float*  a_s    = h + 2097152;                 // 8192*2        = 16384
  float*  a_d    = a_s + 16384;                 // 16384
  float*  gat    = a_d + 16384;                 // 2097152
  float*  hA     = gat + 2097152;               // 8192*128      = 1048576
  float*  h1     = hA + 1048576;                // 8192*64       = 524288
  float*  z      = h1 + 524288;                 // 8192*4        = 32768
  float2* exv    = (float2*)(z + 32768);        // E_TOT float2  = 1064960 floats
  int*    deg    = (int*)(exv + E_TOT);         // 8192
  int*    offs   = deg + 8192;                  // 8200
  int*    cursor = offs + 8200;                 // 8192
  int*    sorted = cursor + 8192;               // E_TOT = 532480

  // zero the histogram
  hipMemsetAsync(deg, 0, N_NODES * sizeof(int), stream);

  // 1. h = x @ W_gat
  gemm_xw_k<<<dim3(4, 128), 256, 0, stream>>>(x, W_gat, h);
  // 2. attention scores
  att_scores_k<<<2048, 256, 0, stream>>>(h, att_src, att_dst, a_s, a_d);
  // 3. counting sort by dst (self-loops folded in via scan's +1)
  hist_k<<<E_EDGES / 256, 256, 0, stream>>>(ei, deg);
  scan_k<<<1, 256, 0, stream>>>(deg, offs, cursor);
  scatter_k<<<E_TOT / 256, 256, 0, stream>>>(ei, a_s, a_d, cursor, sorted, exv);
  // 4. fused softmax + message aggregation (gather, no atomics, no shfl)
  gat_gather_k<<<2048, 256, 0, stream>>>(sorted, exv, offs, h, gat);
  // 5. fused layers (last one also produces z)
  fused_layer_k<256, 128, true,  false><<<N_NODES / 16, 256, 0, stream>>>(gat, bias_gat, w_a, b_a, g_a, be_a, hA, nullptr, nullptr, nullptr);
  fused_layer_k<128, 64,  false, false><<<N_NODES / 16, 256, 0, stream>>>(hA, nullptr, w1, b1, g1, be1, h1, nullptr, nullptr, nullptr);
  fused_layer_k<64,  32,  false, true ><<<N_NODES / 16, 256, 0, stream>>>(h1, nullptr, w2, b2, g2, be2, nullptr, w3, b3, z);
  // 6. pairwise distances
  cdist_k<<<N_NODES * 8, 256, 0, stream>>>(z, out);
}

// Round 4
// 461.876 us; speedup vs baseline: 1.1326x; 1.0434x over previous
//
#include <hip/hip_runtime.h>
#include <hip/hip_bf16.h>

#define N_NODES 8192
#define E_EDGES 524288
#define F_IN    256
#define NH      2
#define F_OUT   128
#define C0      256   // NH*F_OUT
#define E_TOT   (E_EDGES + N_NODES)   // edges + self-loops

typedef float f32x4 __attribute__((ext_vector_type(4)));
typedef _Float16 f16x4 __attribute__((ext_vector_type(4)));

// ---------------- GEMM1: h[8192x256] = x[8192x256] @ W[256x256] ----------------
__global__ __launch_bounds__(256) void gemm_xw_k(const float* __restrict__ A,
                                                 const float* __restrict__ B,
                                                 float* __restrict__ C) {
  const int K = 256, NC = 256;
  __shared__ float As[16][68];  // [k][m]  (pad 68: rows stay 16B-aligned)
  __shared__ float Bs[16][68];  // [k][n]
  int bm = blockIdx.y * 64;
  int bn = blockIdx.x * 64;
  int tid = threadIdx.x;
  int tm = (tid >> 4) << 2;
  int tn = (tid & 15) << 2;
  float acc[4][4] = {};
  for (int k0 = 0; k0 < K; k0 += 16) {
#pragma unroll
    for (int i = 0; i < 4; i++) {
      int idx = tid + i * 256;
      int m = idx >> 4, k = idx & 15;
      As[k][m] = A[(bm + m) * K + k0 + k];
    }
#pragma unroll
    for (int i = 0; i < 4; i++) {
      int idx = tid + i * 256;
      int k = idx >> 6, n = idx & 63;
      Bs[k][n] = B[(k0 + k) * NC + bn + n];
    }
    __syncthreads();
#pragma unroll
    for (int k = 0; k < 16; k++) {
      float4 a = *(const float4*)&As[k][tm];
      float4 b = *(const float4*)&Bs[k][tn];
      acc[0][0] += a.x * b.x; acc[0][1] += a.x * b.y; acc[0][2] += a.x * b.z; acc[0][3] += a.x * b.w;
      acc[1][0] += a.y * b.x; acc[1][1] += a.y * b.y; acc[1][2] += a.y * b.z; acc[1][3] += a.y * b.w;
      acc[2][0] += a.z * b.x; acc[2][1] += a.z * b.y; acc[2][2] += a.z * b.z; acc[2][3] += a.z * b.w;
      acc[3][0] += a.w * b.x; acc[3][1] += a.w * b.y; acc[3][2] += a.w * b.z; acc[3][3] += a.w * b.w;
    }
    __syncthreads();
  }
#pragma unroll
  for (int i = 0; i < 4; i++) {
    float4 o = {acc[i][0], acc[i][1], acc[i][2], acc[i][3]};
    *(float4*)&C[(bm + tm + i) * NC + bn + tn] = o;
  }
}

// ---------------- attention scores + fp16 copy of h ----------------
// Reads each h row once: computes a_s/a_d dots AND writes h16 (RTNE).
__global__ __launch_bounds__(256) void att_scores_k(const float* __restrict__ h,
                                                    const float* __restrict__ att_src,
                                                    const float* __restrict__ att_dst,
                                                    float* __restrict__ a_s,
                                                    float* __restrict__ a_d,
                                                    _Float16* __restrict__ h16) {
  int wave = threadIdx.x >> 6;
  int lane = threadIdx.x & 63;
  int node = blockIdx.x * 4 + wave;
  if (node >= N_NODES) return;
  const float4 hv = *(const float4*)(h + (size_t)node * C0 + lane * 4);
  // fp16 copy for the gather (row = 512B)
  f16x4 hh;
  hh.x = (_Float16)hv.x; hh.y = (_Float16)hv.y;
  hh.z = (_Float16)hv.z; hh.w = (_Float16)hv.w;
  *(f16x4*)(h16 + (size_t)node * C0 + lane * 4) = hh;
  const float4 vs = *(const float4*)(att_src + lane * 4);
  const float4 vd = *(const float4*)(att_dst + lane * 4);
  float s = hv.x * vs.x + hv.y * vs.y + hv.z * vs.z + hv.w * vs.w;
  float d = hv.x * vd.x + hv.y * vd.y + hv.z * vd.z + hv.w * vd.w;
#pragma unroll
  for (int off = 16; off; off >>= 1) {
    s += __shfl_xor(s, off);
    d += __shfl_xor(d, off);
  }
  if (lane == 0)  { a_s[node * 2] = s;     a_d[node * 2] = d; }
  if (lane == 32) { a_s[node * 2 + 1] = s; a_d[node * 2 + 1] = d; }
}

// ---------------- counting sort by dst: histogram (real edges only) ----------------
__global__ __launch_bounds__(256) void hist_k(const int* __restrict__ ei,
                                              int* __restrict__ deg) {
  int e = blockIdx.x * 256 + threadIdx.x;
  if (e < E_EDGES) atomicAdd(&deg[ei[E_EDGES + e]], 1);
}

// ---------------- exclusive scan of (deg+1) per node (single block) ----------------
__global__ __launch_bounds__(256) void scan_k(const int* __restrict__ deg,
                                              int* __restrict__ offs,
                                              int* __restrict__ cursor) {
  __shared__ int sums[256];
  int t = threadIdx.x;
  int local[32];
  int s = 0;
#pragma unroll
  for (int i = 0; i < 32; i++) { local[i] = s; s += deg[t * 32 + i] + 1; }
  sums[t] = s;
  __syncthreads();
  for (int off = 1; off < 256; off <<= 1) {
    int u = (t >= off) ? sums[t - off] : 0;
    __syncthreads();
    if (t >= off) sums[t] += u;
    __syncthreads();
  }
  int base = sums[t] - s;
#pragma unroll
  for (int i = 0; i < 32; i++) {
    int o = base + local[i];
    offs[t * 32 + i] = o;
    cursor[t * 32 + i] = o;
  }
  if (t == 255) offs[N_NODES] = sums[255];   // == E_TOT
}

// ---------------- scatter: sorted src ids + precomputed per-edge exp (both heads) ----------------
__global__ __launch_bounds__(256) void scatter_k(const int* __restrict__ ei,
                                                 const float* __restrict__ a_s,
                                                 const float* __restrict__ a_d,
                                                 int* __restrict__ cursor,
                                                 int* __restrict__ sorted_src,
                                                 float2* __restrict__ exv) {
  int e = blockIdx.x * 256 + threadIdx.x;
  if (e >= E_TOT) return;
  int s, d;
  if (e < E_EDGES) { s = ei[e]; d = ei[E_EDGES + e]; }
  else             { s = d = e - E_EDGES; }
  const float2 as = ((const float2*)a_s)[s];
  const float2 ad = ((const float2*)a_d)[d];
  float v0 = as.x + ad.x; v0 = v0 > 0.0f ? v0 : 0.2f * v0;
  float v1 = as.y + ad.y; v1 = v1 > 0.0f ? v1 : 0.2f * v1;
  int p = atomicAdd(&cursor[d], 1);
  sorted_src[p] = s;
  exv[p] = make_float2(__expf(v0), __expf(v1));
}

// ---------------- gather: one wave per dst node, fp16 h rows (512B), 4x unroll ----------------
__global__ __launch_bounds__(256) void gat_gather_k(const int* __restrict__ sorted_src,
                                                    const float2* __restrict__ exv,
                                                    const int* __restrict__ offs,
                                                    const _Float16* __restrict__ h16,
                                                    float* __restrict__ gat) {
  int wave = threadIdx.x >> 6;
  int lane = threadIdx.x & 63;
  int node = blockIdx.x * 4 + wave;
  if (node >= N_NODES) return;
  int start = __builtin_amdgcn_readfirstlane(offs[node]);
  int end   = __builtin_amdgcn_readfirstlane(offs[node + 1]);
  int head = lane >> 5;
  float4 acc = {0, 0, 0, 0};
  float den = 0.0f;
  int e = start;
  for (; e + 4 <= end; e += 4) {
    int s0 = sorted_src[e];
    int s1 = sorted_src[e + 1];
    int s2 = sorted_src[e + 2];
    int s3 = sorted_src[e + 3];
    float2 x0 = exv[e];
    float2 x1 = exv[e + 1];
    float2 x2 = exv[e + 2];
    float2 x3 = exv[e + 3];
    f16x4 hv0 = *(const f16x4*)(h16 + (size_t)s0 * C0 + lane * 4);
    f16x4 hv1 = *(const f16x4*)(h16 + (size_t)s1 * C0 + lane * 4);
    f16x4 hv2 = *(const f16x4*)(h16 + (size_t)s2 * C0 + lane * 4);
    f16x4 hv3 = *(const f16x4*)(h16 + (size_t)s3 * C0 + lane * 4);
    float w0 = head ? x0.y : x0.x;
    float w1 = head ? x1.y : x1.x;
    float w2 = head ? x2.y : x2.x;
    float w3 = head ? x3.y : x3.x;
    den += (w0 + w1) + (w2 + w3);
    acc.x = fmaf((float)hv0.x, w0, acc.x); acc.y = fmaf((float)hv0.y, w0, acc.y);
    acc.z = fmaf((float)hv0.z, w0, acc.z); acc.w = fmaf((float)hv0.w, w0, acc.w);
    acc.x = fmaf((float)hv1.x, w1, acc.x); acc.y = fmaf((float)hv1.y, w1, acc.y);
    acc.z = fmaf((float)hv1.z, w1, acc.z); acc.w = fmaf((float)hv1.w, w1, acc.w);
    acc.x = fmaf((float)hv2.x, w2, acc.x); acc.y = fmaf((float)hv2.y, w2, acc.y);
    acc.z = fmaf((float)hv2.z, w2, acc.z); acc.w = fmaf((float)hv2.w, w2, acc.w);
    acc.x = fmaf((float)hv3.x, w3, acc.x); acc.y = fmaf((float)hv3.y, w3, acc.y);
    acc.z = fmaf((float)hv3.z, w3, acc.z); acc.w = fmaf((float)hv3.w, w3, acc.w);
  }
  for (; e < end; e++) {
    int s0 = sorted_src[e];
    float2 x0 = exv[e];
    f16x4 hv0 = *(const f16x4*)(h16 + (size_t)s0 * C0 + lane * 4);
    float w0 = head ? x0.y : x0.x;
    den += w0;
    acc.x = fmaf((float)hv0.x, w0, acc.x); acc.y = fmaf((float)hv0.y, w0, acc.y);
    acc.z = fmaf((float)hv0.z, w0, acc.z); acc.w = fmaf((float)hv0.w, w0, acc.w);
  }
  float inv = 1.0f / (den + 1e-16f);
  float4 o = {acc.x * inv, acc.y * inv, acc.z * inv, acc.w * inv};
  *(float4*)(gat + (size_t)node * C0 + lane * 4) = o;
}

// ---------------- fused GEMM + LayerNorm + ReLU per layer (+ optional z projection) ----------------
template <int KDIM, int ODIM, bool APPLY_IN, bool FUSE_Z>
__global__ __launch_bounds__(256) void fused_layer_k(const float* __restrict__ in,
                                                     const float* __restrict__ bias_in,
                                                     const float* __restrict__ W,
                                                     const float* __restrict__ b,
                                                     const float* __restrict__ g,
                                                     const float* __restrict__ be,
                                                     float* __restrict__ out,
                                                     const float* __restrict__ w3,
                                                     const float* __restrict__ b3,
                                                     float* __restrict__ zout) {
  const int TILE = 16;
  const int GROUPS = 256 / ODIM;
  const int NPT = TILE / GROUPS;
  __shared__ float in_t[TILE][KDIM + 4];
  __shared__ float out_t[TILE][ODIM + 1];
  int tid = threadIdx.x;
  int n0 = blockIdx.x * TILE;
  const int KD4 = KDIM / 4;
  for (int idx = tid; idx < TILE * KD4; idx += 256) {
    int n = idx / KD4, k4 = idx % KD4;
    float4 v = *(const float4*)&in[(size_t)(n0 + n) * KDIM + k4 * 4];
    if (APPLY_IN) {
      const float4 bb = *(const float4*)&bias_in[k4 * 4];
      v.x = fmaxf(v.x + bb.x, 0.0f);
      v.y = fmaxf(v.y + bb.y, 0.0f);
      v.z = fmaxf(v.z + bb.z, 0.0f);
      v.w = fmaxf(v.w + bb.w, 0.0f);
    }
    *(float4*)&in_t[n][k4 * 4] = v;
  }
  __syncthreads();
  int jj = tid % ODIM;
  int grp = tid / ODIM;
  float acc[NPT];
#pragma unroll
  for (int t = 0; t < NPT; t++) acc[t] = b[jj];
  for (int k = 0; k < KDIM; k += 4) {
    float w0 = W[(k + 0) * ODIM + jj];
    float w1 = W[(k + 1) * ODIM + jj];
    float w2 = W[(k + 2) * ODIM + jj];
    float w3v = W[(k + 3) * ODIM + jj];
#pragma unroll
    for (int t = 0; t < NPT; t++) {
      float4 v = *(const float4*)&in_t[grp + t * GROUPS][k];
      acc[t] = fmaf(v.w, w3v, fmaf(v.z, w2, fmaf(v.y, w1, fmaf(v.x, w0, acc[t]))));
    }
  }
#pragma unroll
  for (int t = 0; t < NPT; t++) out_t[grp + t * GROUPS][jj] = acc[t];
  __syncthreads();
  const int TPN = 256 / TILE;   // 16
  const int JPT = ODIM / TPN;
  int node = tid / TPN;
  int ln = tid % TPN;
  float v[JPT];
  float s = 0;
#pragma unroll
  for (int q = 0; q < JPT; q++) { v[q] = out_t[node][ln + q * TPN]; s += v[q]; }
#pragma unroll
  for (int m = 1; m < TPN; m <<= 1) s += __shfl_xor(s, m);
  float mu = s / (float)ODIM;
  float vs = 0;
#pragma unroll
  for (int q = 0; q < JPT; q++) { float dd = v[q] - mu; vs += dd * dd; }
#pragma unroll
  for (int m = 1; m < TPN; m <<= 1) vs += __shfl_xor(vs, m);
  float inv = rsqrtf(vs / (float)ODIM + 1e-5f);
  if (FUSE_Z) {
    float p0 = 0, p1 = 0, p2 = 0;
#pragma unroll
    for (int q = 0; q < JPT; q++) {
      int j = ln + q * TPN;
      float val = fmaxf((v[q] - mu) * inv * g[j] + be[j], 0.0f);
      p0 = fmaf(val, w3[j * 3 + 0], p0);
      p1 = fmaf(val, w3[j * 3 + 1], p1);
      p2 = fmaf(val, w3[j * 3 + 2], p2);
    }
#pragma unroll
    for (int m = 1; m < TPN; m <<= 1) {
      p0 += __shfl_xor(p0, m);
      p1 += __shfl_xor(p1, m);
      p2 += __shfl_xor(p2, m);
    }
    if (ln == 0) {
      float4 zz = {p0 + b3[0], p1 + b3[1], p2 + b3[2], 0.0f};
      ((float4*)zout)[n0 + node] = zz;
    }
  } else {
#pragma unroll
    for (int q = 0; q < JPT; q++) {
      int j = ln + q * TPN;
      float o = (v[q] - mu) * inv * g[j] + be[j];
      out[(size_t)(n0 + node) * ODIM + j] = fmaxf(o, 0.0f);
    }
  }
}

// ---------------- cdist: out[i][j] = ||z_i - z_j|| (nontemporal stores) ----------------
__global__ __launch_bounds__(256) void cdist_k(const float* __restrict__ z,
                                               float* __restrict__ out) {
  int i = blockIdx.x >> 3;
  int j0 = (((blockIdx.x & 7) << 8) + threadIdx.x) << 2;  // first of 4 nodes
  const float4 zi = ((const float4*)z)[i];
  f32x4 r;
  {
    float4 zj = ((const float4*)z)[j0 + 0];
    float dx = zi.x - zj.x, dy = zi.y - zj.y, dz = zi.z - zj.z;
    r.x = sqrtf(dx * dx + dy * dy + dz * dz);
  }
  {
    float4 zj = ((const float4*)z)[j0 + 1];
    float dx = zi.x - zj.x, dy = zi.y - zj.y, dz = zi.z - zj.z;
    r.y = sqrtf(dx * dx + dy * dy + dz * dz);
  }
  {
    float4 zj = ((const float4*)z)[j0 + 2];
    float dx = zi.x - zj.x, dy = zi.y - zj.y, dz = zi.z - zj.z;
    r.z = sqrtf(dx * dx + dy * dy + dz * dz);
  }
  {
    float4 zj = ((const float4*)z)[j0 + 3];
    float dx = zi.x - zj.x, dy = zi.y - zj.y, dz = zi.z - zj.z;
    r.w = sqrtf(dx * dx + dy * dy + dz * dz);
  }
  f32x4* dst = (f32x4*)out + (((size_t)i * N_NODES + j0) >> 2);
  __builtin_nontemporal_store(r, dst);
}

extern "C" void kernel_launch(void* const* d_in, const int* in_sizes, int n_in,
                              void* d_out, int out_size, void* d_ws, size_t ws_size,
                              hipStream_t stream) {
  const float* x        = (const float*)d_in[0];
  const int*   ei       = (const int*)d_in[1];
  const float* W_gat    = (const float*)d_in[2];
  const float* att_src  = (const float*)d_in[3];
  const float* att_dst  = (const float*)d_in[4];
  const float* bias_gat = (const float*)d_in[5];
  const float* w_a      = (const float*)d_in[6];
  const float* b_a      = (const float*)d_in[7];
  const float* g_a      = (const float*)d_in[8];
  const float* be_a     = (const float*)d_in[9];
  const float* w1       = (const float*)d_in[10];
  const float* b1       = (const float*)d_in[11];
  const float* g1       = (const float*)d_in[12];
  const float* be1      = (const float*)d_in[13];
  const float* w2       = (const float*)d_in[14];
  const float* b2       = (const float*)d_in[15];
  const float* g2       = (const float*)d_in[16];
  const float* be2      = (const float*)d_in[17];
  const float* w3       = (const float*)d_in[18];
  const float* b3       = (const float*)d_in[19];
  float* out = (float*)d_out;

  float* ws = (float*)d_ws;
  float*    h      = ws;                          // 2097152 floats
  float*    a_s    = h + 2097152;                 // 16384
  float*    a_d    = a_s + 16384;                 // 16384
  float*    gat    = a_d + 16384;                 // 2097152
  float*    hA     = gat + 2097152;               // 1048576
  float*    h1     = hA + 1048576;                // 524288
  float*    z      = h1 + 524288;                 // 32768
  float2*   exv    = (float2*)(z + 32768);        // E_TOT float2 = 1064960 floats
  _Float16* h16    = (_Float16*)((float*)(exv + E_TOT));  // 2097152 halves = 1048576 floats
  int*      deg    = (int*)((float*)h16 + 1048576);       // 8192
  int*      offs   = deg + 8192;                  // 8200
  int*      cursor = offs + 8200;                 // 8192
  int*      sorted = cursor + 8192;               // E_TOT

  // zero the histogram
  hipMemsetAsync(deg, 0, N_NODES * sizeof(int), stream);

  // 1. h = x @ W_gat
  gemm_xw_k<<<dim3(4, 128), 256, 0, stream>>>(x, W_gat, h);
  // 2. attention scores + fp16 copy of h
  att_scores_k<<<2048, 256, 0, stream>>>(h, att_src, att_dst, a_s, a_d, h16);
  // 3. counting sort by dst (self-loops folded in via scan's +1)
  hist_k<<<E_EDGES / 256, 256, 0, stream>>>(ei, deg);
  scan_k<<<1, 256, 0, stream>>>(deg, offs, cursor);
  scatter_k<<<E_TOT / 256, 256, 0, stream>>>(ei, a_s, a_d, cursor, sorted, exv);
  // 4. fused softmax + message aggregation (fp16 rows, L2-resident)
  gat_gather_k<<<2048, 256, 0, stream>>>(sorted, exv, offs, h16, gat);
  // 5. fused layers (last one also produces z)
  fused_layer_k<256, 128, true,  false><<<N_NODES / 16, 256, 0, stream>>>(gat, bias_gat, w_a, b_a, g_a, be_a, hA, nullptr, nullptr, nullptr);
  fused_layer_k<128, 64,  false, false><<<N_NODES / 16, 256, 0, stream>>>(hA, nullptr, w1, b1, g1, be1, h1, nullptr, nullptr, nullptr);
  fused_layer_k<64,  32,  false, true ><<<N_NODES / 16, 256, 0, stream>>>(h1, nullptr, w2, b2, g2, be2, nullptr, w3, b3, z);
  // 6. pairwise distances
  cdist_k<<<N_NODES * 8, 256, 0, stream>>>(z, out);
}

// Round 5
// 455.482 us; speedup vs baseline: 1.1485x; 1.0140x over previous
//
#include <hip/hip_runtime.h>
#include <hip/hip_bf16.h>

#define N_NODES 8192
#define E_EDGES 524288
#define F_IN    256
#define NH      2
#define F_OUT   128
#define C0      256   // NH*F_OUT
#define E_TOT   (E_EDGES + N_NODES)   // edges + self-loops

typedef float f32x4 __attribute__((ext_vector_type(4)));
typedef _Float16 f16x4 __attribute__((ext_vector_type(4)));

// ---------------- GEMM1 + fused attention scores + fp16 h ----------------
// h = x @ W_gat computed in registers; epilogue writes h16 (fp16) and
// accumulates partial a_s/a_d dot products via 2 atomics/row/block.
__global__ __launch_bounds__(256) void gemm_xw_k(const float* __restrict__ A,
                                                 const float* __restrict__ B,
                                                 const float* __restrict__ att_src,
                                                 const float* __restrict__ att_dst,
                                                 _Float16* __restrict__ h16,
                                                 float* __restrict__ a_s,
                                                 float* __restrict__ a_d) {
  const int K = 256, NC = 256;
  __shared__ float As[16][68];  // [k][m]  (pad 68: rows stay 16B-aligned)
  __shared__ float Bs[16][68];  // [k][n]
  int bm = blockIdx.y * 64;
  int bn = blockIdx.x * 64;
  int tid = threadIdx.x;
  int tm = (tid >> 4) << 2;
  int tn = (tid & 15) << 2;
  float acc[4][4] = {};
  for (int k0 = 0; k0 < K; k0 += 16) {
#pragma unroll
    for (int i = 0; i < 4; i++) {
      int idx = tid + i * 256;
      int m = idx >> 4, k = idx & 15;
      As[k][m] = A[(bm + m) * K + k0 + k];
    }
#pragma unroll
    for (int i = 0; i < 4; i++) {
      int idx = tid + i * 256;
      int k = idx >> 6, n = idx & 63;
      Bs[k][n] = B[(k0 + k) * NC + bn + n];
    }
    __syncthreads();
#pragma unroll
    for (int k = 0; k < 16; k++) {
      float4 a = *(const float4*)&As[k][tm];
      float4 b = *(const float4*)&Bs[k][tn];
      acc[0][0] += a.x * b.x; acc[0][1] += a.x * b.y; acc[0][2] += a.x * b.z; acc[0][3] += a.x * b.w;
      acc[1][0] += a.y * b.x; acc[1][1] += a.y * b.y; acc[1][2] += a.y * b.z; acc[1][3] += a.y * b.w;
      acc[2][0] += a.z * b.x; acc[2][1] += a.z * b.y; acc[2][2] += a.z * b.z; acc[2][3] += a.z * b.w;
      acc[3][0] += a.w * b.x; acc[3][1] += a.w * b.y; acc[3][2] += a.w * b.z; acc[3][3] += a.w * b.w;
    }
    __syncthreads();
  }
  // epilogue: fp16 h + partial attention dots
  int head = bn >> 7;   // cols [bn, bn+63] lie entirely in one head
  const float4 asv = *(const float4*)(att_src + bn + tn);
  const float4 adv = *(const float4*)(att_dst + bn + tn);
#pragma unroll
  for (int i = 0; i < 4; i++) {
    int row = bm + tm + i;
    f16x4 hh;
    hh.x = (_Float16)acc[i][0]; hh.y = (_Float16)acc[i][1];
    hh.z = (_Float16)acc[i][2]; hh.w = (_Float16)acc[i][3];
    *(f16x4*)(h16 + (size_t)row * C0 + bn + tn) = hh;
    float ps = acc[i][0] * asv.x + acc[i][1] * asv.y + acc[i][2] * asv.z + acc[i][3] * asv.w;
    float pd = acc[i][0] * adv.x + acc[i][1] * adv.y + acc[i][2] * adv.z + acc[i][3] * adv.w;
#pragma unroll
    for (int m = 1; m < 16; m <<= 1) { ps += __shfl_xor(ps, m); pd += __shfl_xor(pd, m); }
    if ((tid & 15) == 0) {
      atomicAdd(&a_s[row * 2 + head], ps);
      atomicAdd(&a_d[row * 2 + head], pd);
    }
  }
}

// ---------------- counting sort by dst: histogram (real edges only) ----------------
__global__ __launch_bounds__(256) void hist_k(const int* __restrict__ ei,
                                              int* __restrict__ deg) {
  int e = blockIdx.x * 256 + threadIdx.x;
  if (e < E_EDGES) atomicAdd(&deg[ei[E_EDGES + e]], 1);
}

// ---------------- exclusive scan of (deg+1) per node (single block) ----------------
__global__ __launch_bounds__(256) void scan_k(const int* __restrict__ deg,
                                              int* __restrict__ offs,
                                              int* __restrict__ cursor) {
  __shared__ int sums[256];
  int t = threadIdx.x;
  int local[32];
  int s = 0;
#pragma unroll
  for (int i = 0; i < 32; i++) { local[i] = s; s += deg[t * 32 + i] + 1; }
  sums[t] = s;
  __syncthreads();
  for (int off = 1; off < 256; off <<= 1) {
    int u = (t >= off) ? sums[t - off] : 0;
    __syncthreads();
    if (t >= off) sums[t] += u;
    __syncthreads();
  }
  int base = sums[t] - s;
#pragma unroll
  for (int i = 0; i < 32; i++) {
    int o = base + local[i];
    offs[t * 32 + i] = o;
    cursor[t * 32 + i] = o;
  }
  if (t == 255) offs[N_NODES] = sums[255];   // == E_TOT
}

// ---------------- scatter: sorted src ids + precomputed per-edge exp (both heads) ----------------
__global__ __launch_bounds__(256) void scatter_k(const int* __restrict__ ei,
                                                 const float* __restrict__ a_s,
                                                 const float* __restrict__ a_d,
                                                 int* __restrict__ cursor,
                                                 int* __restrict__ sorted_src,
                                                 float2* __restrict__ exv) {
  int e = blockIdx.x * 256 + threadIdx.x;
  if (e >= E_TOT) return;
  int s, d;
  if (e < E_EDGES) { s = ei[e]; d = ei[E_EDGES + e]; }
  else             { s = d = e - E_EDGES; }
  const float2 as = ((const float2*)a_s)[s];
  const float2 ad = ((const float2*)a_d)[d];
  float v0 = as.x + ad.x; v0 = v0 > 0.0f ? v0 : 0.2f * v0;
  float v1 = as.y + ad.y; v1 = v1 > 0.0f ? v1 : 0.2f * v1;
  int p = atomicAdd(&cursor[d], 1);
  sorted_src[p] = s;
  exv[p] = make_float2(__expf(v0), __expf(v1));
}

// ---------------- gather: one wave per dst node, fp16 h rows (512B), 4x unroll ----------------
__global__ __launch_bounds__(256) void gat_gather_k(const int* __restrict__ sorted_src,
                                                    const float2* __restrict__ exv,
                                                    const int* __restrict__ offs,
                                                    const _Float16* __restrict__ h16,
                                                    float* __restrict__ gat) {
  int wave = threadIdx.x >> 6;
  int lane = threadIdx.x & 63;
  int node = blockIdx.x * 4 + wave;
  if (node >= N_NODES) return;
  int start = __builtin_amdgcn_readfirstlane(offs[node]);
  int end   = __builtin_amdgcn_readfirstlane(offs[node + 1]);
  int head = lane >> 5;
  float4 acc = {0, 0, 0, 0};
  float den = 0.0f;
  int e = start;
  for (; e + 4 <= end; e += 4) {
    int s0 = sorted_src[e];
    int s1 = sorted_src[e + 1];
    int s2 = sorted_src[e + 2];
    int s3 = sorted_src[e + 3];
    float2 x0 = exv[e];
    float2 x1 = exv[e + 1];
    float2 x2 = exv[e + 2];
    float2 x3 = exv[e + 3];
    f16x4 hv0 = *(const f16x4*)(h16 + (size_t)s0 * C0 + lane * 4);
    f16x4 hv1 = *(const f16x4*)(h16 + (size_t)s1 * C0 + lane * 4);
    f16x4 hv2 = *(const f16x4*)(h16 + (size_t)s2 * C0 + lane * 4);
    f16x4 hv3 = *(const f16x4*)(h16 + (size_t)s3 * C0 + lane * 4);
    float w0 = head ? x0.y : x0.x;
    float w1 = head ? x1.y : x1.x;
    float w2 = head ? x2.y : x2.x;
    float w3 = head ? x3.y : x3.x;
    den += (w0 + w1) + (w2 + w3);
    acc.x = fmaf((float)hv0.x, w0, acc.x); acc.y = fmaf((float)hv0.y, w0, acc.y);
    acc.z = fmaf((float)hv0.z, w0, acc.z); acc.w = fmaf((float)hv0.w, w0, acc.w);
    acc.x = fmaf((float)hv1.x, w1, acc.x); acc.y = fmaf((float)hv1.y, w1, acc.y);
    acc.z = fmaf((float)hv1.z, w1, acc.z); acc.w = fmaf((float)hv1.w, w1, acc.w);
    acc.x = fmaf((float)hv2.x, w2, acc.x); acc.y = fmaf((float)hv2.y, w2, acc.y);
    acc.z = fmaf((float)hv2.z, w2, acc.z); acc.w = fmaf((float)hv2.w, w2, acc.w);
    acc.x = fmaf((float)hv3.x, w3, acc.x); acc.y = fmaf((float)hv3.y, w3, acc.y);
    acc.z = fmaf((float)hv3.z, w3, acc.z); acc.w = fmaf((float)hv3.w, w3, acc.w);
  }
  for (; e < end; e++) {
    int s0 = sorted_src[e];
    float2 x0 = exv[e];
    f16x4 hv0 = *(const f16x4*)(h16 + (size_t)s0 * C0 + lane * 4);
    float w0 = head ? x0.y : x0.x;
    den += w0;
    acc.x = fmaf((float)hv0.x, w0, acc.x); acc.y = fmaf((float)hv0.y, w0, acc.y);
    acc.z = fmaf((float)hv0.z, w0, acc.z); acc.w = fmaf((float)hv0.w, w0, acc.w);
  }
  float inv = 1.0f / (den + 1e-16f);
  float4 o = {acc.x * inv, acc.y * inv, acc.z * inv, acc.w * inv};
  *(float4*)(gat + (size_t)node * C0 + lane * 4) = o;
}

// ---------------- full MLP: 3 x (GEMM + LN + ReLU) + z projection, one kernel ----------------
// One block = 16 nodes; LDS ping-pong 256 -> 128 -> 64 -> 32 -> z[3].
template <int KDIM, int ODIM>
__device__ __forceinline__ void layer_gemm(const float (*in_t)[KDIM + 4],
                                           float (*out_t)[ODIM + 4],
                                           const float* __restrict__ W,
                                           const float* __restrict__ b,
                                           int tid) {
  const int GROUPS = 256 / ODIM;
  const int NPT = 16 / GROUPS;
  int jj = tid % ODIM;
  int grp = tid / ODIM;
  float acc[NPT];
#pragma unroll
  for (int t = 0; t < NPT; t++) acc[t] = b[jj];
  for (int k = 0; k < KDIM; k += 4) {
    float w0 = W[(k + 0) * ODIM + jj];
    float w1 = W[(k + 1) * ODIM + jj];
    float w2 = W[(k + 2) * ODIM + jj];
    float w3v = W[(k + 3) * ODIM + jj];
#pragma unroll
    for (int t = 0; t < NPT; t++) {
      float4 v = *(const float4*)&in_t[grp + t * GROUPS][k];
      acc[t] = fmaf(v.w, w3v, fmaf(v.z, w2, fmaf(v.y, w1, fmaf(v.x, w0, acc[t]))));
    }
  }
#pragma unroll
  for (int t = 0; t < NPT; t++) out_t[grp + t * GROUPS][jj] = acc[t];
}

template <int ODIM>
__device__ __forceinline__ void layer_ln_relu(float (*buf)[ODIM + 4],
                                              const float* __restrict__ g,
                                              const float* __restrict__ be,
                                              int tid) {
  const int TPN = 16;
  const int JPT = ODIM / TPN;
  int node = tid / TPN;
  int ln = tid % TPN;
  float v[JPT];
  float s = 0;
#pragma unroll
  for (int q = 0; q < JPT; q++) { v[q] = buf[node][ln + q * TPN]; s += v[q]; }
#pragma unroll
  for (int m = 1; m < TPN; m <<= 1) s += __shfl_xor(s, m);
  float mu = s / (float)ODIM;
  float vs = 0;
#pragma unroll
  for (int q = 0; q < JPT; q++) { float dd = v[q] - mu; vs += dd * dd; }
#pragma unroll
  for (int m = 1; m < TPN; m <<= 1) vs += __shfl_xor(vs, m);
  float inv = rsqrtf(vs / (float)ODIM + 1e-5f);
#pragma unroll
  for (int q = 0; q < JPT; q++) {
    int j = ln + q * TPN;
    buf[node][j] = fmaxf((v[q] - mu) * inv * g[j] + be[j], 0.0f);
  }
}

__global__ __launch_bounds__(256) void mlp_all_k(const float* __restrict__ gat,
                                                 const float* __restrict__ bias_gat,
                                                 const float* __restrict__ w_a,
                                                 const float* __restrict__ b_a,
                                                 const float* __restrict__ g_a,
                                                 const float* __restrict__ be_a,
                                                 const float* __restrict__ w1,
                                                 const float* __restrict__ b1,
                                                 const float* __restrict__ g1,
                                                 const float* __restrict__ be1,
                                                 const float* __restrict__ w2,
                                                 const float* __restrict__ b2,
                                                 const float* __restrict__ g2,
                                                 const float* __restrict__ be2,
                                                 const float* __restrict__ w3,
                                                 const float* __restrict__ b3,
                                                 float* __restrict__ z) {
  __shared__ float bufA[16][260];
  __shared__ float bufB[16][132];
  __shared__ float bufC[16][68];
  __shared__ float bufD[16][36];
  int tid = threadIdx.x;
  int n0 = blockIdx.x * 16;
  // load input tile: relu(gat + bias_gat)
  for (int idx = tid; idx < 16 * 64; idx += 256) {
    int n = idx >> 6, k4 = idx & 63;
    float4 v = *(const float4*)&gat[(size_t)(n0 + n) * 256 + k4 * 4];
    const float4 bb = *(const float4*)&bias_gat[k4 * 4];
    v.x = fmaxf(v.x + bb.x, 0.0f);
    v.y = fmaxf(v.y + bb.y, 0.0f);
    v.z = fmaxf(v.z + bb.z, 0.0f);
    v.w = fmaxf(v.w + bb.w, 0.0f);
    *(float4*)&bufA[n][k4 * 4] = v;
  }
  __syncthreads();
  layer_gemm<256, 128>(bufA, bufB, w_a, b_a, tid);
  __syncthreads();
  layer_ln_relu<128>(bufB, g_a, be_a, tid);
  __syncthreads();
  layer_gemm<128, 64>(bufB, bufC, w1, b1, tid);
  __syncthreads();
  layer_ln_relu<64>(bufC, g1, be1, tid);
  __syncthreads();
  layer_gemm<64, 32>(bufC, bufD, w2, b2, tid);
  __syncthreads();
  // final LN + relu + 3-col projection, 16 threads per node
  {
    const int TPN = 16, JPT = 2;
    int node = tid / TPN;
    int ln = tid % TPN;
    float v[JPT];
    float s = 0;
#pragma unroll
    for (int q = 0; q < JPT; q++) { v[q] = bufD[node][ln + q * TPN]; s += v[q]; }
#pragma unroll
    for (int m = 1; m < TPN; m <<= 1) s += __shfl_xor(s, m);
    float mu = s / 32.0f;
    float vs = 0;
#pragma unroll
    for (int q = 0; q < JPT; q++) { float dd = v[q] - mu; vs += dd * dd; }
#pragma unroll
    for (int m = 1; m < TPN; m <<= 1) vs += __shfl_xor(vs, m);
    float inv = rsqrtf(vs / 32.0f + 1e-5f);
    float p0 = 0, p1 = 0, p2 = 0;
#pragma unroll
    for (int q = 0; q < JPT; q++) {
      int j = ln + q * TPN;
      float val = fmaxf((v[q] - mu) * inv * g2[j] + be2[j], 0.0f);
      p0 = fmaf(val, w3[j * 3 + 0], p0);
      p1 = fmaf(val, w3[j * 3 + 1], p1);
      p2 = fmaf(val, w3[j * 3 + 2], p2);
    }
#pragma unroll
    for (int m = 1; m < TPN; m <<= 1) {
      p0 += __shfl_xor(p0, m);
      p1 += __shfl_xor(p1, m);
      p2 += __shfl_xor(p2, m);
    }
    if (ln == 0) {
      float4 zz = {p0 + b3[0], p1 + b3[1], p2 + b3[2], 0.0f};
      ((float4*)z)[n0 + node] = zz;
    }
  }
}

// ---------------- cdist: out[i][j] = ||z_i - z_j|| (nontemporal stores) ----------------
__global__ __launch_bounds__(256) void cdist_k(const float* __restrict__ z,
                                               float* __restrict__ out) {
  int i = blockIdx.x >> 3;
  int j0 = (((blockIdx.x & 7) << 8) + threadIdx.x) << 2;  // first of 4 nodes
  const float4 zi = ((const float4*)z)[i];
  f32x4 r;
  {
    float4 zj = ((const float4*)z)[j0 + 0];
    float dx = zi.x - zj.x, dy = zi.y - zj.y, dz = zi.z - zj.z;
    r.x = sqrtf(dx * dx + dy * dy + dz * dz);
  }
  {
    float4 zj = ((const float4*)z)[j0 + 1];
    float dx = zi.x - zj.x, dy = zi.y - zj.y, dz = zi.z - zj.z;
    r.y = sqrtf(dx * dx + dy * dy + dz * dz);
  }
  {
    float4 zj = ((const float4*)z)[j0 + 2];
    float dx = zi.x - zj.x, dy = zi.y - zj.y, dz = zi.z - zj.z;
    r.z = sqrtf(dx * dx + dy * dy + dz * dz);
  }
  {
    float4 zj = ((const float4*)z)[j0 + 3];
    float dx = zi.x - zj.x, dy = zi.y - zj.y, dz = zi.z - zj.z;
    r.w = sqrtf(dx * dx + dy * dy + dz * dz);
  }
  f32x4* dst = (f32x4*)out + (((size_t)i * N_NODES + j0) >> 2);
  __builtin_nontemporal_store(r, dst);
}

extern "C" void kernel_launch(void* const* d_in, const int* in_sizes, int n_in,
                              void* d_out, int out_size, void* d_ws, size_t ws_size,
                              hipStream_t stream) {
  const float* x        = (const float*)d_in[0];
  const int*   ei       = (const int*)d_in[1];
  const float* W_gat    = (const float*)d_in[2];
  const float* att_src  = (const float*)d_in[3];
  const float* att_dst  = (const float*)d_in[4];
  const float* bias_gat = (const float*)d_in[5];
  const float* w_a      = (const float*)d_in[6];
  const float* b_a      = (const float*)d_in[7];
  const float* g_a      = (const float*)d_in[8];
  const float* be_a     = (const float*)d_in[9];
  const float* w1       = (const float*)d_in[10];
  const float* b1       = (const float*)d_in[11];
  const float* g1       = (const float*)d_in[12];
  const float* be1      = (const float*)d_in[13];
  const float* w2       = (const float*)d_in[14];
  const float* b2       = (const float*)d_in[15];
  const float* g2       = (const float*)d_in[16];
  const float* be2      = (const float*)d_in[17];
  const float* w3       = (const float*)d_in[18];
  const float* b3       = (const float*)d_in[19];
  float* out = (float*)d_out;

  float* ws = (float*)d_ws;
  float*    a_s    = ws;                          // 16384 (zeroed)
  float*    a_d    = a_s + 16384;                 // 16384 (zeroed)
  int*      deg    = (int*)(a_d + 16384);         // 8192  (zeroed)
  _Float16* h16    = (_Float16*)(deg + 8192);     // 2097152 halves = 1048576 floats
  float*    gat    = (float*)h16 + 1048576;       // 2097152
  float*    z      = gat + 2097152;               // 32768
  float2*   exv    = (float2*)(z + 32768);        // E_TOT float2
  int*      offs   = (int*)(exv + E_TOT);         // 8200
  int*      cursor = offs + 8200;                 // 8192
  int*      sorted = cursor + 8192;               // E_TOT

  // zero a_s, a_d, deg in one shot (contiguous)
  hipMemsetAsync(a_s, 0, (16384 + 16384 + 8192) * sizeof(float), stream);

  // 1. h16 = fp16(x @ W_gat) + attention score partials
  gemm_xw_k<<<dim3(4, 128), 256, 0, stream>>>(x, W_gat, att_src, att_dst, h16, a_s, a_d);
  // 2. counting sort by dst (self-loops folded in via scan's +1)
  hist_k<<<E_EDGES / 256, 256, 0, stream>>>(ei, deg);
  scan_k<<<1, 256, 0, stream>>>(deg, offs, cursor);
  scatter_k<<<E_TOT / 256, 256, 0, stream>>>(ei, a_s, a_d, cursor, sorted, exv);
  // 3. fused softmax + message aggregation (fp16 rows, L2-resident)
  gat_gather_k<<<2048, 256, 0, stream>>>(sorted, exv, offs, h16, gat);
  // 4. whole MLP + z projection in one kernel
  mlp_all_k<<<N_NODES / 16, 256, 0, stream>>>(gat, bias_gat, w_a, b_a, g_a, be_a,
                                              w1, b1, g1, be1, w2, b2, g2, be2, w3, b3, z);
  // 5. pairwise distances
  cdist_k<<<N_NODES * 8, 256, 0, stream>>>(z, out);
}

// Round 6
// 438.921 us; speedup vs baseline: 1.1919x; 1.0377x over previous
//
#include <hip/hip_runtime.h>
#include <hip/hip_bf16.h>

#define N_NODES 8192
#define E_EDGES 524288
#define F_IN    256
#define NH      2
#define F_OUT   128
#define C0      256   // NH*F_OUT
#define E_TOT   (E_EDGES + N_NODES)   // edges + self-loops

typedef float f32x4 __attribute__((ext_vector_type(4)));
typedef _Float16 f16x4 __attribute__((ext_vector_type(4)));

// ---------------- GEMM1 + fused attention scores + fp16 h ----------------
__global__ __launch_bounds__(256) void gemm_xw_k(const float* __restrict__ A,
                                                 const float* __restrict__ B,
                                                 const float* __restrict__ att_src,
                                                 const float* __restrict__ att_dst,
                                                 _Float16* __restrict__ h16,
                                                 float* __restrict__ a_s,
                                                 float* __restrict__ a_d) {
  const int K = 256, NC = 256;
  __shared__ float As[16][68];  // [k][m]  (pad 68: rows stay 16B-aligned)
  __shared__ float Bs[16][68];  // [k][n]
  int bm = blockIdx.y * 64;
  int bn = blockIdx.x * 64;
  int tid = threadIdx.x;
  int tm = (tid >> 4) << 2;
  int tn = (tid & 15) << 2;
  float acc[4][4] = {};
  for (int k0 = 0; k0 < K; k0 += 16) {
#pragma unroll
    for (int i = 0; i < 4; i++) {
      int idx = tid + i * 256;
      int m = idx >> 4, k = idx & 15;
      As[k][m] = A[(bm + m) * K + k0 + k];
    }
#pragma unroll
    for (int i = 0; i < 4; i++) {
      int idx = tid + i * 256;
      int k = idx >> 6, n = idx & 63;
      Bs[k][n] = B[(k0 + k) * NC + bn + n];
    }
    __syncthreads();
#pragma unroll
    for (int k = 0; k < 16; k++) {
      float4 a = *(const float4*)&As[k][tm];
      float4 b = *(const float4*)&Bs[k][tn];
      acc[0][0] += a.x * b.x; acc[0][1] += a.x * b.y; acc[0][2] += a.x * b.z; acc[0][3] += a.x * b.w;
      acc[1][0] += a.y * b.x; acc[1][1] += a.y * b.y; acc[1][2] += a.y * b.z; acc[1][3] += a.y * b.w;
      acc[2][0] += a.z * b.x; acc[2][1] += a.z * b.y; acc[2][2] += a.z * b.z; acc[2][3] += a.z * b.w;
      acc[3][0] += a.w * b.x; acc[3][1] += a.w * b.y; acc[3][2] += a.w * b.z; acc[3][3] += a.w * b.w;
    }
    __syncthreads();
  }
  // epilogue: fp16 h + partial attention dots
  int head = bn >> 7;   // cols [bn, bn+63] lie entirely in one head
  const float4 asv = *(const float4*)(att_src + bn + tn);
  const float4 adv = *(const float4*)(att_dst + bn + tn);
#pragma unroll
  for (int i = 0; i < 4; i++) {
    int row = bm + tm + i;
    f16x4 hh;
    hh.x = (_Float16)acc[i][0]; hh.y = (_Float16)acc[i][1];
    hh.z = (_Float16)acc[i][2]; hh.w = (_Float16)acc[i][3];
    *(f16x4*)(h16 + (size_t)row * C0 + bn + tn) = hh;
    float ps = acc[i][0] * asv.x + acc[i][1] * asv.y + acc[i][2] * asv.z + acc[i][3] * asv.w;
    float pd = acc[i][0] * adv.x + acc[i][1] * adv.y + acc[i][2] * adv.z + acc[i][3] * adv.w;
#pragma unroll
    for (int m = 1; m < 16; m <<= 1) { ps += __shfl_xor(ps, m); pd += __shfl_xor(pd, m); }
    if ((tid & 15) == 0) {
      atomicAdd(&a_s[row * 2 + head], ps);
      atomicAdd(&a_d[row * 2 + head], pd);
    }
  }
}

// ---------------- counting sort by dst: histogram (real edges only) ----------------
__global__ __launch_bounds__(256) void hist_k(const int* __restrict__ ei,
                                              int* __restrict__ deg) {
  int e = blockIdx.x * 256 + threadIdx.x;
  if (e < E_EDGES) atomicAdd(&deg[ei[E_EDGES + e]], 1);
}

// ---------------- exclusive scan of (deg+1) per node (single block) ----------------
__global__ __launch_bounds__(256) void scan_k(const int* __restrict__ deg,
                                              int* __restrict__ offs,
                                              int* __restrict__ cursor) {
  __shared__ int sums[256];
  int t = threadIdx.x;
  int local[32];
  int s = 0;
#pragma unroll
  for (int i = 0; i < 32; i++) { local[i] = s; s += deg[t * 32 + i] + 1; }
  sums[t] = s;
  __syncthreads();
  for (int off = 1; off < 256; off <<= 1) {
    int u = (t >= off) ? sums[t - off] : 0;
    __syncthreads();
    if (t >= off) sums[t] += u;
    __syncthreads();
  }
  int base = sums[t] - s;
#pragma unroll
  for (int i = 0; i < 32; i++) {
    int o = base + local[i];
    offs[t * 32 + i] = o;
    cursor[t * 32 + i] = o;
  }
  if (t == 255) offs[N_NODES] = sums[255];   // == E_TOT
}

// ---------------- scatter: sorted src ids + precomputed per-edge exp (both heads) ----------------
__global__ __launch_bounds__(256) void scatter_k(const int* __restrict__ ei,
                                                 const float* __restrict__ a_s,
                                                 const float* __restrict__ a_d,
                                                 int* __restrict__ cursor,
                                                 int* __restrict__ sorted_src,
                                                 float2* __restrict__ exv) {
  int e = blockIdx.x * 256 + threadIdx.x;
  if (e >= E_TOT) return;
  int s, d;
  if (e < E_EDGES) { s = ei[e]; d = ei[E_EDGES + e]; }
  else             { s = d = e - E_EDGES; }
  const float2 as = ((const float2*)a_s)[s];
  const float2 ad = ((const float2*)a_d)[d];
  float v0 = as.x + ad.x; v0 = v0 > 0.0f ? v0 : 0.2f * v0;
  float v1 = as.y + ad.y; v1 = v1 > 0.0f ? v1 : 0.2f * v1;
  int p = atomicAdd(&cursor[d], 1);
  sorted_src[p] = s;
  exv[p] = make_float2(__expf(v0), __expf(v1));
}

// ---------------- gather: one wave per dst node, fp16 h rows (512B), 4x unroll ----------------
__global__ __launch_bounds__(256) void gat_gather_k(const int* __restrict__ sorted_src,
                                                    const float2* __restrict__ exv,
                                                    const int* __restrict__ offs,
                                                    const _Float16* __restrict__ h16,
                                                    float* __restrict__ gat) {
  int wave = threadIdx.x >> 6;
  int lane = threadIdx.x & 63;
  int node = blockIdx.x * 4 + wave;
  if (node >= N_NODES) return;
  int start = __builtin_amdgcn_readfirstlane(offs[node]);
  int end   = __builtin_amdgcn_readfirstlane(offs[node + 1]);
  int head = lane >> 5;
  float4 acc = {0, 0, 0, 0};
  float den = 0.0f;
  int e = start;
  for (; e + 4 <= end; e += 4) {
    int s0 = sorted_src[e];
    int s1 = sorted_src[e + 1];
    int s2 = sorted_src[e + 2];
    int s3 = sorted_src[e + 3];
    float2 x0 = exv[e];
    float2 x1 = exv[e + 1];
    float2 x2 = exv[e + 2];
    float2 x3 = exv[e + 3];
    f16x4 hv0 = *(const f16x4*)(h16 + (size_t)s0 * C0 + lane * 4);
    f16x4 hv1 = *(const f16x4*)(h16 + (size_t)s1 * C0 + lane * 4);
    f16x4 hv2 = *(const f16x4*)(h16 + (size_t)s2 * C0 + lane * 4);
    f16x4 hv3 = *(const f16x4*)(h16 + (size_t)s3 * C0 + lane * 4);
    float w0 = head ? x0.y : x0.x;
    float w1 = head ? x1.y : x1.x;
    float w2 = head ? x2.y : x2.x;
    float w3 = head ? x3.y : x3.x;
    den += (w0 + w1) + (w2 + w3);
    acc.x = fmaf((float)hv0.x, w0, acc.x); acc.y = fmaf((float)hv0.y, w0, acc.y);
    acc.z = fmaf((float)hv0.z, w0, acc.z); acc.w = fmaf((float)hv0.w, w0, acc.w);
    acc.x = fmaf((float)hv1.x, w1, acc.x); acc.y = fmaf((float)hv1.y, w1, acc.y);
    acc.z = fmaf((float)hv1.z, w1, acc.z); acc.w = fmaf((float)hv1.w, w1, acc.w);
    acc.x = fmaf((float)hv2.x, w2, acc.x); acc.y = fmaf((float)hv2.y, w2, acc.y);
    acc.z = fmaf((float)hv2.z, w2, acc.z); acc.w = fmaf((float)hv2.w, w2, acc.w);
    acc.x = fmaf((float)hv3.x, w3, acc.x); acc.y = fmaf((float)hv3.y, w3, acc.y);
    acc.z = fmaf((float)hv3.z, w3, acc.z); acc.w = fmaf((float)hv3.w, w3, acc.w);
  }
  for (; e < end; e++) {
    int s0 = sorted_src[e];
    float2 x0 = exv[e];
    f16x4 hv0 = *(const f16x4*)(h16 + (size_t)s0 * C0 + lane * 4);
    float w0 = head ? x0.y : x0.x;
    den += w0;
    acc.x = fmaf((float)hv0.x, w0, acc.x); acc.y = fmaf((float)hv0.y, w0, acc.y);
    acc.z = fmaf((float)hv0.z, w0, acc.z); acc.w = fmaf((float)hv0.w, w0, acc.w);
  }
  float inv = 1.0f / (den + 1e-16f);
  float4 o = {acc.x * inv, acc.y * inv, acc.z * inv, acc.w * inv};
  *(float4*)(gat + (size_t)node * C0 + lane * 4) = o;
}

// ---------------- full MLP: 3 x (GEMM + LN + ReLU) + z projection, one kernel ----------------
template <int KDIM, int ODIM>
__device__ __forceinline__ void layer_gemm(const float (*in_t)[KDIM + 4],
                                           float (*out_t)[ODIM + 4],
                                           const float* __restrict__ W,
                                           const float* __restrict__ b,
                                           int tid) {
  const int GROUPS = 256 / ODIM;
  const int NPT = 16 / GROUPS;
  int jj = tid % ODIM;
  int grp = tid / ODIM;
  float acc[NPT];
#pragma unroll
  for (int t = 0; t < NPT; t++) acc[t] = b[jj];
  for (int k = 0; k < KDIM; k += 4) {
    float w0 = W[(k + 0) * ODIM + jj];
    float w1 = W[(k + 1) * ODIM + jj];
    float w2 = W[(k + 2) * ODIM + jj];
    float w3v = W[(k + 3) * ODIM + jj];
#pragma unroll
    for (int t = 0; t < NPT; t++) {
      float4 v = *(const float4*)&in_t[grp + t * GROUPS][k];
      acc[t] = fmaf(v.w, w3v, fmaf(v.z, w2, fmaf(v.y, w1, fmaf(v.x, w0, acc[t]))));
    }
  }
#pragma unroll
  for (int t = 0; t < NPT; t++) out_t[grp + t * GROUPS][jj] = acc[t];
}

template <int ODIM>
__device__ __forceinline__ void layer_ln_relu(float (*buf)[ODIM + 4],
                                              const float* __restrict__ g,
                                              const float* __restrict__ be,
                                              int tid) {
  const int TPN = 16;
  const int JPT = ODIM / TPN;
  int node = tid / TPN;
  int ln = tid % TPN;
  float v[JPT];
  float s = 0;
#pragma unroll
  for (int q = 0; q < JPT; q++) { v[q] = buf[node][ln + q * TPN]; s += v[q]; }
#pragma unroll
  for (int m = 1; m < TPN; m <<= 1) s += __shfl_xor(s, m);
  float mu = s / (float)ODIM;
  float vs = 0;
#pragma unroll
  for (int q = 0; q < JPT; q++) { float dd = v[q] - mu; vs += dd * dd; }
#pragma unroll
  for (int m = 1; m < TPN; m <<= 1) vs += __shfl_xor(vs, m);
  float inv = rsqrtf(vs / (float)ODIM + 1e-5f);
#pragma unroll
  for (int q = 0; q < JPT; q++) {
    int j = ln + q * TPN;
    buf[node][j] = fmaxf((v[q] - mu) * inv * g[j] + be[j], 0.0f);
  }
}

__global__ __launch_bounds__(256) void mlp_all_k(const float* __restrict__ gat,
                                                 const float* __restrict__ bias_gat,
                                                 const float* __restrict__ w_a,
                                                 const float* __restrict__ b_a,
                                                 const float* __restrict__ g_a,
                                                 const float* __restrict__ be_a,
                                                 const float* __restrict__ w1,
                                                 const float* __restrict__ b1,
                                                 const float* __restrict__ g1,
                                                 const float* __restrict__ be1,
                                                 const float* __restrict__ w2,
                                                 const float* __restrict__ b2,
                                                 const float* __restrict__ g2,
                                                 const float* __restrict__ be2,
                                                 const float* __restrict__ w3,
                                                 const float* __restrict__ b3,
                                                 float* __restrict__ z) {
  __shared__ float bufA[16][260];
  __shared__ float bufB[16][132];
  __shared__ float bufC[16][68];
  __shared__ float bufD[16][36];
  int tid = threadIdx.x;
  int n0 = blockIdx.x * 16;
  for (int idx = tid; idx < 16 * 64; idx += 256) {
    int n = idx >> 6, k4 = idx & 63;
    float4 v = *(const float4*)&gat[(size_t)(n0 + n) * 256 + k4 * 4];
    const float4 bb = *(const float4*)&bias_gat[k4 * 4];
    v.x = fmaxf(v.x + bb.x, 0.0f);
    v.y = fmaxf(v.y + bb.y, 0.0f);
    v.z = fmaxf(v.z + bb.z, 0.0f);
    v.w = fmaxf(v.w + bb.w, 0.0f);
    *(float4*)&bufA[n][k4 * 4] = v;
  }
  __syncthreads();
  layer_gemm<256, 128>(bufA, bufB, w_a, b_a, tid);
  __syncthreads();
  layer_ln_relu<128>(bufB, g_a, be_a, tid);
  __syncthreads();
  layer_gemm<128, 64>(bufB, bufC, w1, b1, tid);
  __syncthreads();
  layer_ln_relu<64>(bufC, g1, be1, tid);
  __syncthreads();
  layer_gemm<64, 32>(bufC, bufD, w2, b2, tid);
  __syncthreads();
  {
    const int TPN = 16, JPT = 2;
    int node = tid / TPN;
    int ln = tid % TPN;
    float v[JPT];
    float s = 0;
#pragma unroll
    for (int q = 0; q < JPT; q++) { v[q] = bufD[node][ln + q * TPN]; s += v[q]; }
#pragma unroll
    for (int m = 1; m < TPN; m <<= 1) s += __shfl_xor(s, m);
    float mu = s / 32.0f;
    float vs = 0;
#pragma unroll
    for (int q = 0; q < JPT; q++) { float dd = v[q] - mu; vs += dd * dd; }
#pragma unroll
    for (int m = 1; m < TPN; m <<= 1) vs += __shfl_xor(vs, m);
    float inv = rsqrtf(vs / 32.0f + 1e-5f);
    float p0 = 0, p1 = 0, p2 = 0;
#pragma unroll
    for (int q = 0; q < JPT; q++) {
      int j = ln + q * TPN;
      float val = fmaxf((v[q] - mu) * inv * g2[j] + be2[j], 0.0f);
      p0 = fmaf(val, w3[j * 3 + 0], p0);
      p1 = fmaf(val, w3[j * 3 + 1], p1);
      p2 = fmaf(val, w3[j * 3 + 2], p2);
    }
#pragma unroll
    for (int m = 1; m < TPN; m <<= 1) {
      p0 += __shfl_xor(p0, m);
      p1 += __shfl_xor(p1, m);
      p2 += __shfl_xor(p2, m);
    }
    if (ln == 0) {
      float4 zz = {p0 + b3[0], p1 + b3[1], p2 + b3[2], 0.0f};
      ((float4*)z)[n0 + node] = zz;
    }
  }
}

// ---------------- cdist v3: 1024 blocks x 8 rows, z-reads amortized 8x ----------------
#define TI 8
__global__ __launch_bounds__(256) void cdist_k(const float* __restrict__ z,
                                               float* __restrict__ out) {
  int i0 = blockIdx.x * TI;
  int t = threadIdx.x;
  float4 zi[TI];
#pragma unroll
  for (int r = 0; r < TI; r++) zi[r] = ((const float4*)z)[i0 + r];
#pragma unroll
  for (int c = 0; c < 8; c++) {
    int j0 = (c * 256 + t) << 2;   // 4 j-nodes per thread per chunk
    float4 zj0 = ((const float4*)z)[j0 + 0];
    float4 zj1 = ((const float4*)z)[j0 + 1];
    float4 zj2 = ((const float4*)z)[j0 + 2];
    float4 zj3 = ((const float4*)z)[j0 + 3];
#pragma unroll
    for (int r = 0; r < TI; r++) {
      f32x4 o;
      {
        float dx = zi[r].x - zj0.x, dy = zi[r].y - zj0.y, dz = zi[r].z - zj0.z;
        o.x = sqrtf(dx * dx + dy * dy + dz * dz);
      }
      {
        float dx = zi[r].x - zj1.x, dy = zi[r].y - zj1.y, dz = zi[r].z - zj1.z;
        o.y = sqrtf(dx * dx + dy * dy + dz * dz);
      }
      {
        float dx = zi[r].x - zj2.x, dy = zi[r].y - zj2.y, dz = zi[r].z - zj2.z;
        o.z = sqrtf(dx * dx + dy * dy + dz * dz);
      }
      {
        float dx = zi[r].x - zj3.x, dy = zi[r].y - zj3.y, dz = zi[r].z - zj3.z;
        o.w = sqrtf(dx * dx + dy * dy + dz * dz);
      }
      f32x4* dst = (f32x4*)out + (((size_t)(i0 + r) * N_NODES + j0) >> 2);
      __builtin_nontemporal_store(o, dst);
    }
  }
}

extern "C" void kernel_launch(void* const* d_in, const int* in_sizes, int n_in,
                              void* d_out, int out_size, void* d_ws, size_t ws_size,
                              hipStream_t stream) {
  const float* x        = (const float*)d_in[0];
  const int*   ei       = (const int*)d_in[1];
  const float* W_gat    = (const float*)d_in[2];
  const float* att_src  = (const float*)d_in[3];
  const float* att_dst  = (const float*)d_in[4];
  const float* bias_gat = (const float*)d_in[5];
  const float* w_a      = (const float*)d_in[6];
  const float* b_a      = (const float*)d_in[7];
  const float* g_a      = (const float*)d_in[8];
  const float* be_a     = (const float*)d_in[9];
  const float* w1       = (const float*)d_in[10];
  const float* b1       = (const float*)d_in[11];
  const float* g1       = (const float*)d_in[12];
  const float* be1      = (const float*)d_in[13];
  const float* w2       = (const float*)d_in[14];
  const float* b2       = (const float*)d_in[15];
  const float* g2       = (const float*)d_in[16];
  const float* be2      = (const float*)d_in[17];
  const float* w3       = (const float*)d_in[18];
  const float* b3       = (const float*)d_in[19];
  float* out = (float*)d_out;

  float* ws = (float*)d_ws;
  float*    a_s    = ws;                          // 16384 (zeroed)
  float*    a_d    = a_s + 16384;                 // 16384 (zeroed)
  int*      deg    = (int*)(a_d + 16384);         // 8192  (zeroed)
  _Float16* h16    = (_Float16*)(deg + 8192);     // 2097152 halves = 1048576 floats
  float*    gat    = (float*)h16 + 1048576;       // 2097152
  float*    z      = gat + 2097152;               // 32768
  float2*   exv    = (float2*)(z + 32768);        // E_TOT float2
  int*      offs   = (int*)(exv + E_TOT);         // 8200
  int*      cursor = offs + 8200;                 // 8192
  int*      sorted = cursor + 8192;               // E_TOT

  // zero a_s, a_d, deg in one shot (contiguous)
  hipMemsetAsync(a_s, 0, (16384 + 16384 + 8192) * sizeof(float), stream);

  // 1. h16 = fp16(x @ W_gat) + attention score partials
  gemm_xw_k<<<dim3(4, 128), 256, 0, stream>>>(x, W_gat, att_src, att_dst, h16, a_s, a_d);
  // 2. counting sort by dst (self-loops folded in via scan's +1)
  hist_k<<<E_EDGES / 256, 256, 0, stream>>>(ei, deg);
  scan_k<<<1, 256, 0, stream>>>(deg, offs, cursor);
  scatter_k<<<E_TOT / 256, 256, 0, stream>>>(ei, a_s, a_d, cursor, sorted, exv);
  // 3. fused softmax + message aggregation (fp16 rows, L2-resident)
  gat_gather_k<<<2048, 256, 0, stream>>>(sorted, exv, offs, h16, gat);
  // 4. whole MLP + z projection in one kernel
  mlp_all_k<<<N_NODES / 16, 256, 0, stream>>>(gat, bias_gat, w_a, b_a, g_a, be_a,
                                              w1, b1, g1, be1, w2, b2, g2, be2, w3, b3, z);
  // 5. pairwise distances (1024 fat blocks)
  cdist_k<<<N_NODES / TI, 256, 0, stream>>>(z, out);
}